// Round 3
// baseline (872.581 us; speedup 1.0000x reference)
//
#include <hip/hip_runtime.h>
#include <math.h>

// ---------------- problem constants ----------------
#define NB 4096
#define ND 1024

// d_out float offsets
#define O_ZC   0
#define O_ZD   262144
#define O_MU   327680
#define O_LV   393216
#define O_A    458752
#define O_DAG  462848
#define O_HSIC 462849
#define O_KL   462850

// ws byte offsets (zeroed region: [0, WS_ZEND))
#define WS_CNT    64u
#define WS_H1C    256u
#define WS_H1D    33024u
#define WS_M2C    65792u
#define WS_M2D    131328u
#define WS_RSC    196864u
#define WS_RSD    213248u
#define WS_ZEND   229632u
// non-zeroed scratch
#define WS_XNC    229632u
#define WS_XND    246016u
#define WS_WC     262400u
#define WS_CST    786688u
#define WS_W1T0   787200u
#define WS_W1T1   803584u
#define WS_B1T    819968u
#define WS_W2T    836352u
#define WS_U      852736u
#define WS_DH     1901312u
#define WS_LISTC  2949888u
#define WS_LISTD  4784896u

#define C_CAP 458752u
#define D_CAP 589824u

// fast erf-based gelu: A&S 7.1.26, |err| <= 1.5e-7, branch-free
__device__ __forceinline__ float gelu_f(float x){
  float y = fabsf(x) * 0.70710678118654752440f;
  float t = 1.0f / (1.0f + 0.3275911f * y);
  float poly = t*(0.254829592f + t*(-0.284496736f + t*(1.421413741f + t*(-1.453152027f + t*1.061405429f))));
  float e = __expf(-y*y);
  float er = 1.0f - poly*e;
  float s = copysignf(er, x);
  return 0.5f * x * (1.0f + s);
}

// triangle block map: b -> (bi <= bj), b = bj*(bj+1)/2 + bi
__device__ __forceinline__ void tri_map(int b, int& bi, int& bj){
  int r = (int)((sqrtf(8.0f*(float)b + 1.0f) - 1.0f) * 0.5f);
  while ((r+1)*(r+2)/2 <= b) r++;
  while (r*(r+1)/2 > b) r--;
  bj = r; bi = b - r*(r+1)/2;
}

// ---------------- zero scratch ----------------
__global__ __launch_bounds__(256) void k_zero(uint4* p, int n){
  uint4 z; z.x = 0; z.y = 0; z.z = 0; z.w = 0;
  for (int i = blockIdx.x*256 + threadIdx.x; i < n; i += gridDim.x*256) p[i] = z;
}

// ---------------- prep: folded weights, A, consts, causal transposes ----------------
__global__ __launch_bounds__(256) void k_prep(
    const float* __restrict__ ln_g, const float* __restrict__ ln_b,
    const float* __restrict__ W_u,  const float* __restrict__ b_u,
    const float* __restrict__ dln_g,const float* __restrict__ dln_b,
    const float* __restrict__ W_db, const float* __restrict__ b_db,
    const float* __restrict__ adj,  const float* __restrict__ W1,
    const float* __restrict__ b1,   const float* __restrict__ W2,
    float* __restrict__ Wc, float* __restrict__ cst,
    float* __restrict__ w1t0, float* __restrict__ w1t1,
    float* __restrict__ b1t,  float* __restrict__ w2t,
    float* __restrict__ outA){
  __shared__ float red[256];
  int t = threadIdx.x, b = blockIdx.x;
  if (b < 512){
    int e = b*256 + t; int c = e & 127, d = e >> 7;
    Wc[e] = (c < 64) ? ln_g[d]*W_u[d*64 + c] : dln_g[d]*W_db[d*64 + (c-64)];
  } else if (b < 528){
    int e = (b-512)*256 + t; int i = e >> 6, j = e & 63;
    float a = 1.0f/(1.0f + __expf(-adj[e]));
    outA[e] = (i == j) ? 0.0f : a;
  } else if (b < 656){
    int col = b - 528;
    float p = 0.0f;
    for (int d = t; d < 1024; d += 256)
      p += (col < 64) ? ln_b[d]*W_u[d*64 + col] : dln_b[d]*W_db[d*64 + (col-64)];
    red[t] = p; __syncthreads();
    for (int off = 128; off > 0; off >>= 1){ if (t < off) red[t] += red[t+off]; __syncthreads(); }
    if (t == 0) cst[col] = red[0] + ((col < 64) ? b_u[col] : b_db[col-64]);
  } else {
    int e = (b-656)*256 + t; int which = e >> 12, r = e & 4095;
    int j = r >> 6, k = r & 63;
    if (which == 0)      w1t0[j*64+k] = W1[k*128 + j];
    else if (which == 1) w1t1[j*64+k] = W1[k*128 + 64 + j];
    else if (which == 2) b1t [j*64+k] = b1[k*64 + j];
    else                 w2t [j*64+k] = W2[k*64 + j];
  }
}

// ---------------- LN + dual GEMM (u pre-bias, dh pre-gelu) ----------------
__global__ __launch_bounds__(512) void k_lngemm(const float* __restrict__ feat,
    const float* __restrict__ Wc, const float* __restrict__ cst,
    float* __restrict__ u_ws, float* __restrict__ dh_ws){
  __shared__ float xh[16][1024];   // 64KB
  int t = threadIdx.x, b = blockIdx.x;
  {
    int row = t >> 5, lane = t & 31;
    const float4* src = (const float4*)(feat + (b*16 + row)*1024);
    float4 v[8]; float s = 0.0f, s2 = 0.0f;
    #pragma unroll
    for (int q = 0; q < 8; q++){
      v[q] = src[lane + q*32];
      s += v[q].x + v[q].y + v[q].z + v[q].w;
      s2 = fmaf(v[q].x,v[q].x, fmaf(v[q].y,v[q].y, fmaf(v[q].z,v[q].z, fmaf(v[q].w,v[q].w, s2))));
    }
    #pragma unroll
    for (int off = 1; off < 32; off <<= 1){ s += __shfl_xor(s, off); s2 += __shfl_xor(s2, off); }
    float mean = s * (1.0f/1024.0f);
    float var  = s2 * (1.0f/1024.0f) - mean*mean;
    float rs = rsqrtf(var + 1e-5f);
    float4* dst = (float4*)&xh[row][0];
    #pragma unroll
    for (int q = 0; q < 8; q++){
      float4 w; w.x = (v[q].x-mean)*rs; w.y = (v[q].y-mean)*rs;
      w.z = (v[q].z-mean)*rs; w.w = (v[q].w-mean)*rs;
      dst[lane + q*32] = w;
    }
  }
  __syncthreads();
  int col = t & 127, rg = t >> 7;    // rg in [0,4): 4 rows each
  float acc[4] = {0,0,0,0};
  for (int d0 = 0; d0 < 1024; d0 += 4){
    float w0 = Wc[(d0  )*128 + col];
    float w1 = Wc[(d0+1)*128 + col];
    float w2 = Wc[(d0+2)*128 + col];
    float w3 = Wc[(d0+3)*128 + col];
    #pragma unroll
    for (int r = 0; r < 4; r++){
      float4 x = *(const float4*)&xh[rg*4 + r][d0];
      acc[r] = fmaf(x.x,w0, fmaf(x.y,w1, fmaf(x.z,w2, fmaf(x.w,w3, acc[r]))));
    }
  }
  float cc = cst[col];
  #pragma unroll
  for (int r = 0; r < 4; r++){
    int grow = b*16 + rg*4 + r;
    float o = acc[r] + cc;
    if (col < 64) u_ws[grow*64 + col] = o;
    else          dh_ws[grow*64 + (col-64)] = o;
  }
}

// ---------------- causal structural loop (wave per row) ----------------
__global__ __launch_bounds__(256) void k_causal(const float* __restrict__ u_ws,
    const float* __restrict__ A_g, const float* __restrict__ w1t0g, const float* __restrict__ w1t1g,
    const float* __restrict__ b1tg, const float* __restrict__ w2tg, const float* __restrict__ b2_g,
    float* __restrict__ zc_out){
  __shared__ float w1t0[4096], w1t1[4096];
  __shared__ float zbuf[4][64];
  int t = threadIdx.x;
  for (int e = t; e < 4096; e += 256){ w1t0[e] = w1t0g[e]; w1t1[e] = w1t1g[e]; }
  int w = t >> 6, k = t & 63;
  int row = blockIdx.x*4 + w;
  float uu = u_ws[row*64 + k];
  float b2v = b2_g[k];
  float z = uu;
  __syncthreads();
  #pragma unroll
  for (int itr = 0; itr < 2; ++itr){
    zbuf[w][k] = z;
    float p0=0.f,p1=0.f,p2=0.f,p3=0.f;
    #pragma unroll
    for (int j0 = 0; j0 < 64; j0 += 4){
      float4 zz = *(const float4*)&zbuf[w][j0];
      p0 = fmaf(zz.x, A_g[(j0+0)*64 + k], p0);
      p1 = fmaf(zz.y, A_g[(j0+1)*64 + k], p1);
      p2 = fmaf(zz.z, A_g[(j0+2)*64 + k], p2);
      p3 = fmaf(zz.w, A_g[(j0+3)*64 + k], p3);
    }
    float p = (p0+p1)+(p2+p3);
    float a0=0.f, a1=0.f;
    #pragma unroll 8
    for (int j = 0; j < 64; j += 2){
      float pre0 = fmaf(p, w1t0[j*64+k],     fmaf(uu, w1t1[j*64+k],     b1tg[j*64+k]));
      float pre1 = fmaf(p, w1t0[(j+1)*64+k], fmaf(uu, w1t1[(j+1)*64+k], b1tg[(j+1)*64+k]));
      a0 = fmaf(gelu_f(pre0), w2tg[j*64+k],     a0);
      a1 = fmaf(gelu_f(pre1), w2tg[(j+1)*64+k], a1);
    }
    z = a0 + a1 + b2v;
  }
  zc_out[row*64 + k] = z;
}

// ---------------- domain head: gelu, mu/lv, z_d, KL ----------------
__global__ __launch_bounds__(256) void k_domain(const float* __restrict__ dh_ws,
    const float* __restrict__ Wmu, const float* __restrict__ bmu,
    const float* __restrict__ Wlv, const float* __restrict__ blv,
    const float* __restrict__ eps, float* __restrict__ out, double* __restrict__ wsd){
  __shared__ float hb[4][64];
  int t = threadIdx.x, w = t >> 6, l = t & 63;
  int dd = l & 15;
  double klacc = 0.0;
  for (int it = 0; it < 4; ++it){
    int row = blockIdx.x*16 + it*4 + w;
    hb[w][l] = gelu_f(dh_ws[row*64 + l]);
    float val = 0.0f;
    if (l < 32){
      const float* W = (l < 16) ? Wmu : Wlv;
      float a = (l < 16) ? bmu[dd] : blv[dd];
      for (int j = 0; j < 64; j++) a = fmaf(hb[w][j], W[j*16 + dd], a);
      val = a;
    }
    float mu = __shfl(val, dd);
    float lv = __shfl(val, 16 + dd);
    float kle = 0.0f;
    if (l < 16){
      out[O_MU + row*16 + dd] = mu;
      out[O_LV + row*16 + dd] = lv;
      out[O_ZD + row*16 + dd] = fmaf(eps[row*16 + dd], __expf(0.5f*lv), mu);
      kle = 1.0f + lv - mu*mu - __expf(lv);
    }
    #pragma unroll
    for (int off = 1; off < 16; off <<= 1) kle += __shfl_xor(kle, off);
    if (l == 0) klacc += (double)kle;
  }
  if (l == 0) atomicAdd(&wsd[1], klacc);
}

// ---------------- row squared norms ----------------
__global__ __launch_bounds__(256) void k_rownorm(const float* __restrict__ out,
    float* __restrict__ xnc, float* __restrict__ xnd){
  int t = threadIdx.x, w = t >> 6, l = t & 63;
  int row = blockIdx.x*4 + w;
  float zc = out[O_ZC + row*64 + l];
  float a = zc*zc;
  #pragma unroll
  for (int off = 1; off < 64; off <<= 1) a += __shfl_xor(a, off);
  if (l == 0) xnc[row] = a;
  float zd = (l < 16) ? out[O_ZD + row*16 + l] : 0.0f;
  float bs = zd*zd;
  #pragma unroll
  for (int off = 1; off < 16; off <<= 1) bs += __shfl_xor(bs, off);
  if (l == 0) xnd[row] = bs;
}

// ---------------- tile staging + 8x8 dot micro-kernel ----------------
template<int DIM>
__device__ __forceinline__ void stageT(const float* __restrict__ src, float* __restrict__ dst,
                                       int i0, int t){
  for (int e = t; e < DIM*128; e += 256){
    int k = e & (DIM-1);
    int r = e >> (DIM == 64 ? 6 : 4);
    dst[k*128 + (r ^ ((k & 7) << 2))] = src[(i0 + r)*DIM + k];
  }
}

template<int KDIM>
__device__ __forceinline__ void dot8x8(const float* __restrict__ LA, const float* __restrict__ LB,
                                       int tx8, int ty8, float acc[8][8]){
  #pragma unroll 8
  for (int k = 0; k < KDIM; k++){
    int s = (k & 7) << 2;
    const float* pa = LA + k*128;
    const float* pb = LB + k*128;
    float4 a0 = *(const float4*)(pa + ((ty8    ) ^ s));
    float4 a1 = *(const float4*)(pa + ((ty8 + 4) ^ s));
    float4 b0 = *(const float4*)(pb + ((tx8    ) ^ s));
    float4 b1 = *(const float4*)(pb + ((tx8 + 4) ^ s));
    float av[8] = {a0.x,a0.y,a0.z,a0.w,a1.x,a1.y,a1.z,a1.w};
    float bv[8] = {b0.x,b0.y,b0.z,b0.w,b1.x,b1.y,b1.z,b1.w};
    #pragma unroll
    for (int ii = 0; ii < 8; ii++)
      #pragma unroll
      for (int jj = 0; jj < 8; jj++)
        acc[ii][jj] = fmaf(av[ii], bv[jj], acc[ii][jj]);
  }
}

// ---------------- dag: expm via scaling & squaring (single block) ----------------
__device__ void dag_mm(float* __restrict__ C, const float* __restrict__ Am, const float* __restrict__ Bm,
                       const float* __restrict__ Xm, float cI, float cX, int t, bool addG){
  int tx = t & 15, ty = t >> 4;
  float acc[4][4] = {};
  for (int k0 = 0; k0 < 64; k0 += 4){
    float4 a0 = *(const float4*)&Am[(ty*4+0)*64 + k0];
    float4 a1 = *(const float4*)&Am[(ty*4+1)*64 + k0];
    float4 a2 = *(const float4*)&Am[(ty*4+2)*64 + k0];
    float4 a3 = *(const float4*)&Am[(ty*4+3)*64 + k0];
    float4 b0 = *(const float4*)&Bm[(k0+0)*64 + tx*4];
    float4 b1 = *(const float4*)&Bm[(k0+1)*64 + tx*4];
    float4 b2 = *(const float4*)&Bm[(k0+2)*64 + tx*4];
    float4 b3 = *(const float4*)&Bm[(k0+3)*64 + tx*4];
#define MQ(ii, AV) \
    acc[ii][0] = fmaf(AV.x,b0.x, fmaf(AV.y,b1.x, fmaf(AV.z,b2.x, fmaf(AV.w,b3.x, acc[ii][0])))); \
    acc[ii][1] = fmaf(AV.x,b0.y, fmaf(AV.y,b1.y, fmaf(AV.z,b2.y, fmaf(AV.w,b3.y, acc[ii][1])))); \
    acc[ii][2] = fmaf(AV.x,b0.z, fmaf(AV.y,b1.z, fmaf(AV.z,b2.z, fmaf(AV.w,b3.z, acc[ii][2])))); \
    acc[ii][3] = fmaf(AV.x,b0.w, fmaf(AV.y,b1.w, fmaf(AV.z,b2.w, fmaf(AV.w,b3.w, acc[ii][3]))));
    MQ(0,a0) MQ(1,a1) MQ(2,a2) MQ(3,a3)
#undef MQ
  }
  #pragma unroll
  for (int ii = 0; ii < 4; ii++)
    #pragma unroll
    for (int jj = 0; jj < 4; jj++){
      int i = ty*4 + ii, j = tx*4 + jj;
      float v = acc[ii][jj];
      if (addG) v += ((i == j) ? cI : 0.0f) + cX * Xm[i*64 + j];
      C[i*64 + j] = v;
    }
  __syncthreads();
}

__device__ void dag_expm(float* ldsA, float* ldsB, const float* __restrict__ A_g,
                         float* __restrict__ dout){
  int t = threadIdx.x;
  float* X  = ldsA;
  float* X2 = ldsA + 4096;
  float* P  = ldsB;
  float* Pn = ldsB + 4096;
  for (int e = t; e < 4096; e += 256){ float a = A_g[e]; X[e] = a*a; }
  __syncthreads();
  int l = t & 63;
  float cs = 0.0f;
  for (int i = 0; i < 64; i++) cs += X[i*64 + l];
  #pragma unroll
  for (int off = 1; off < 64; off <<= 1) cs = fmaxf(cs, __shfl_xor(cs, off));
  int s_ = 0;
  if (cs > 2.0f) s_ = (int)ceilf(log2f(cs * 0.5f));
  if (s_ < 0) s_ = 0; if (s_ > 12) s_ = 12;
  float sc = exp2f((float)(-s_));
  __syncthreads();
  for (int e = t; e < 4096; e += 256) X[e] *= sc;
  __syncthreads();
  dag_mm(X2, X, X, X, 0.0f, 0.0f, t, false);
  const float C12 = 2.0876756987868099e-9f, C13 = 1.6059043836821613e-10f;
  for (int e = t; e < 4096; e += 256){
    int i = e >> 6, j = e & 63;
    P[e] = C13*X[e] + ((i == j) ? C12 : 0.0f);
  }
  __syncthreads();
  const float cf[12] = {1.0f, 1.0f, 0.5f, 1.0f/6.0f, 1.0f/24.0f, 1.0f/120.0f,
                        1.0f/720.0f, 1.0f/5040.0f, 1.0f/40320.0f, 1.0f/362880.0f,
                        1.0f/3628800.0f, 1.0f/39916800.0f};
  #pragma unroll
  for (int g = 5; g >= 0; --g){
    dag_mm(Pn, X2, P, X, cf[2*g], cf[2*g+1], t, true);
    float* tmp = P; P = Pn; Pn = tmp;
  }
  for (int q = 0; q < s_; ++q){
    dag_mm(Pn, P, P, X, 0.0f, 0.0f, t, false);
    float* tmp = P; P = Pn; Pn = tmp;
  }
  if (t < 64){
    float tr = P[t*65];
    #pragma unroll
    for (int off = 1; off < 64; off <<= 1) tr += __shfl_xor(tr, off);
    if (t == 0) dout[O_DAG] = tr - 64.0f;
  }
}

// ---------------- median pass 1: top-13-bit histograms, triangle (+dag block) ----------------
__global__ __launch_bounds__(256,1) void k_pass1(const float* __restrict__ out,
    const float* __restrict__ xnc, const float* __restrict__ xnd,
    unsigned* __restrict__ h1c, unsigned* __restrict__ h1d, float* __restrict__ dout){
  __shared__ __align__(16) float ldsA[8192];
  __shared__ __align__(16) float ldsB[8192];
  int t = threadIdx.x;
  if (blockIdx.x == 528){ dag_expm(ldsA, ldsB, out + O_A, dout); return; }
  int bi, bj; tri_map(blockIdx.x, bi, bj);
  bool diag = (bi == bj);
  int i0 = bi*128, j0 = bj*128;
  int tx = t & 15, ty = t >> 4, tx8 = tx*8, ty8 = ty*8;
  stageT<64>(out + O_ZC, ldsA, i0, t);
  stageT<64>(out + O_ZC, ldsB, j0, t);
  float xi[8], xj[8];
  #pragma unroll
  for (int ii = 0; ii < 8; ii++){ xi[ii] = xnc[i0+ty8+ii]; xj[ii] = xnc[j0+tx8+ii]; }
  __syncthreads();
  float acc[8][8] = {};
  dot8x8<64>(ldsA, ldsB, tx8, ty8, acc);
  __syncthreads();
  unsigned* hist = (unsigned*)ldsA;
  for (int e = t; e < 8192; e += 256) hist[e] = 0u;
  __syncthreads();
  #pragma unroll
  for (int ii = 0; ii < 8; ii++)
    #pragma unroll
    for (int jj = 0; jj < 8; jj++){
      float d2 = xi[ii] + xj[jj] - 2.0f*acc[ii][jj];
      bool take = diag ? ((i0+ty8+ii) < (j0+tx8+jj)) : true;
      if (take && d2 > 0.0f)
        atomicAdd(&hist[__float_as_uint(d2) >> 19], 1u);
    }
  __syncthreads();
  for (int e = t; e < 8192; e += 256){ unsigned v = hist[e]; if (v) atomicAdd(&h1c[e], v); }
  __syncthreads();
  // d phase
  stageT<16>(out + O_ZD, ldsB, i0, t);
  stageT<16>(out + O_ZD, ldsB + 2048, j0, t);
  #pragma unroll
  for (int ii = 0; ii < 8; ii++){ xi[ii] = xnd[i0+ty8+ii]; xj[ii] = xnd[j0+tx8+ii]; }
  __syncthreads();
  float acd[8][8] = {};
  dot8x8<16>(ldsB, ldsB + 2048, tx8, ty8, acd);
  __syncthreads();
  for (int e = t; e < 8192; e += 256) hist[e] = 0u;
  __syncthreads();
  #pragma unroll
  for (int ii = 0; ii < 8; ii++)
    #pragma unroll
    for (int jj = 0; jj < 8; jj++){
      float d2 = xi[ii] + xj[jj] - 2.0f*acd[ii][jj];
      bool take = diag ? ((i0+ty8+ii) < (j0+tx8+jj)) : true;
      if (take && d2 > 0.0f)
        atomicAdd(&hist[__float_as_uint(d2) >> 19], 1u);
    }
  __syncthreads();
  for (int e = t; e < 8192; e += 256){ unsigned v = hist[e]; if (v) atomicAdd(&h1d[e], v); }
}

// find target bin (and rank within bin) from a level-1 histogram; counts once per pair
__device__ unsigned find_bin(const unsigned* __restrict__ h1, unsigned* sbuf, int t, unsigned* k2out){
  unsigned part = 0;
  for (int i = 0; i < 32; i++) part += h1[t*32 + i];
  sbuf[t] = part;
  __syncthreads();
  for (int off = 1; off < 256; off <<= 1){
    unsigned v = (t >= off) ? sbuf[t-off] : 0u;
    __syncthreads();
    sbuf[t] += v;
    __syncthreads();
  }
  unsigned total = sbuf[255];
  unsigned pre = sbuf[t] - part;
  __syncthreads();
  if (t == 0){ sbuf[0] = 0xFFFFFFFFu; sbuf[1] = 0u; }
  __syncthreads();
  if (total > 0){
    unsigned rt = (total - 1u) >> 1;   // lower median rank
    if (rt >= pre && rt < pre + part){
      unsigned run = pre;
      for (int i = 0; i < 32; i++){
        unsigned c = h1[t*32 + i];
        if (rt < run + c){ sbuf[0] = (unsigned)(t*32 + i); sbuf[1] = rt - run; break; }
        run += c;
      }
    }
  }
  __syncthreads();
  unsigned b1 = sbuf[0];
  unsigned k2 = sbuf[1];
  __syncthreads();
  if (k2out) *k2out = k2;
  return b1;
}

// ---------------- median pass 2: LDS 16384-bin mid hist (bits 18:5) + wave-agg compaction ----------------
__global__ __launch_bounds__(256,1) void k_pass2(const float* __restrict__ out,
    const float* __restrict__ xnc, const float* __restrict__ xnd,
    const unsigned* __restrict__ h1c, const unsigned* __restrict__ h1d,
    unsigned* __restrict__ m2c, unsigned* __restrict__ m2d,
    unsigned* __restrict__ listc, unsigned* __restrict__ listd,
    unsigned* __restrict__ cntg){
  __shared__ __align__(16) float lds[16384];   // 64KB, staging + hist reuse
  float* ldsA = lds;
  float* ldsB = lds + 8192;
  unsigned* hist = (unsigned*)lds;             // 16384 bins after dots
  int t = threadIdx.x;
  int lane = t & 63;
  unsigned b1c = find_bin(h1c, (unsigned*)lds, t, nullptr);
  unsigned b1d = find_bin(h1d, (unsigned*)lds, t, nullptr);
  int bi, bj; tri_map(blockIdx.x, bi, bj);
  bool diag = (bi == bj);
  int i0 = bi*128, j0 = bj*128;
  int tx = t & 15, ty = t >> 4, tx8 = tx*8, ty8 = ty*8;
  // ---- c phase ----
  stageT<64>(out + O_ZC, ldsA, i0, t);
  stageT<64>(out + O_ZC, ldsB, j0, t);
  float xi[8], xj[8];
  #pragma unroll
  for (int ii = 0; ii < 8; ii++){ xi[ii] = xnc[i0+ty8+ii]; xj[ii] = xnc[j0+tx8+ii]; }
  __syncthreads();
  float acc[8][8] = {};
  dot8x8<64>(ldsA, ldsB, tx8, ty8, acc);
  __syncthreads();
  for (int e = t; e < 16384; e += 256) hist[e] = 0u;
  __syncthreads();
  {
    unsigned nmy = 0;
    #pragma unroll
    for (int ii = 0; ii < 8; ii++)
      #pragma unroll
      for (int jj = 0; jj < 8; jj++){
        float d2 = xi[ii] + xj[jj] - 2.0f*acc[ii][jj];
        unsigned u = __float_as_uint(d2);
        bool take = (diag ? ((i0+ty8+ii) < (j0+tx8+jj)) : true) && d2 > 0.0f && (u >> 19) == b1c;
        if (take) nmy++;
      }
    unsigned pref = nmy;
    #pragma unroll
    for (int off = 1; off < 64; off <<= 1){ unsigned v = __shfl_up(pref, off); if (lane >= off) pref += v; }
    unsigned wtot = __shfl(pref, 63);
    unsigned base = 0;
    if (lane == 63 && wtot) base = atomicAdd(&cntg[0], wtot);
    base = __shfl(base, 63);
    unsigned p = base + (pref - nmy);
    #pragma unroll
    for (int ii = 0; ii < 8; ii++)
      #pragma unroll
      for (int jj = 0; jj < 8; jj++){
        float d2 = xi[ii] + xj[jj] - 2.0f*acc[ii][jj];
        unsigned u = __float_as_uint(d2);
        bool take = (diag ? ((i0+ty8+ii) < (j0+tx8+jj)) : true) && d2 > 0.0f && (u >> 19) == b1c;
        if (take){
          atomicAdd(&hist[(u >> 5) & 0x3FFFu], 1u);
          if (p < C_CAP) listc[p] = u & 0x7FFFFu;
          p++;
        }
      }
  }
  __syncthreads();
  for (int e = t; e < 16384; e += 256){ unsigned v = hist[e]; if (v) atomicAdd(&m2c[e], v); }
  __syncthreads();
  // ---- d phase ----
  stageT<16>(out + O_ZD, ldsB, i0, t);
  stageT<16>(out + O_ZD, ldsB + 2048, j0, t);
  #pragma unroll
  for (int ii = 0; ii < 8; ii++){ xi[ii] = xnd[i0+ty8+ii]; xj[ii] = xnd[j0+tx8+ii]; }
  __syncthreads();
  float acd[8][8] = {};
  dot8x8<16>(ldsB, ldsB + 2048, tx8, ty8, acd);
  __syncthreads();
  for (int e = t; e < 16384; e += 256) hist[e] = 0u;
  __syncthreads();
  {
    unsigned nmy = 0;
    #pragma unroll
    for (int ii = 0; ii < 8; ii++)
      #pragma unroll
      for (int jj = 0; jj < 8; jj++){
        float d2 = xi[ii] + xj[jj] - 2.0f*acd[ii][jj];
        unsigned u = __float_as_uint(d2);
        bool take = (diag ? ((i0+ty8+ii) < (j0+tx8+jj)) : true) && d2 > 0.0f && (u >> 19) == b1d;
        if (take) nmy++;
      }
    unsigned pref = nmy;
    #pragma unroll
    for (int off = 1; off < 64; off <<= 1){ unsigned v = __shfl_up(pref, off); if (lane >= off) pref += v; }
    unsigned wtot = __shfl(pref, 63);
    unsigned base = 0;
    if (lane == 63 && wtot) base = atomicAdd(&cntg[1], wtot);
    base = __shfl(base, 63);
    unsigned p = base + (pref - nmy);
    #pragma unroll
    for (int ii = 0; ii < 8; ii++)
      #pragma unroll
      for (int jj = 0; jj < 8; jj++){
        float d2 = xi[ii] + xj[jj] - 2.0f*acd[ii][jj];
        unsigned u = __float_as_uint(d2);
        bool take = (diag ? ((i0+ty8+ii) < (j0+tx8+jj)) : true) && d2 > 0.0f && (u >> 19) == b1d;
        if (take){
          atomicAdd(&hist[(u >> 5) & 0x3FFFu], 1u);
          if (p < D_CAP) listd[p] = u & 0x7FFFFu;
          p++;
        }
      }
  }
  __syncthreads();
  for (int e = t; e < 16384; e += 256){ unsigned v = hist[e]; if (v) atomicAdd(&m2d[e], v); }
}

// ---------------- median finalize: m2 scan (bits 18:5 exact) + list sweep (low 5 exact) ----------------
__global__ __launch_bounds__(256) void k_scan2(const unsigned* __restrict__ h1c,
    const unsigned* __restrict__ h1d, const unsigned* __restrict__ m2c,
    const unsigned* __restrict__ m2d, const unsigned* __restrict__ listc,
    const unsigned* __restrict__ listd, const unsigned* __restrict__ cntg,
    float* __restrict__ wsf){
  __shared__ unsigned sbuf[256];
  __shared__ unsigned res[4];
  __shared__ unsigned h32[32];
  int t = threadIdx.x;
  bool isd = blockIdx.x != 0;
  const unsigned* h1   = isd ? h1d   : h1c;
  const unsigned* m2   = isd ? m2d   : m2c;
  const unsigned* list = isd ? listd : listc;
  unsigned CAP = isd ? D_CAP : C_CAP;
  unsigned k2;
  unsigned b1 = find_bin(h1, sbuf, t, &k2);
  if (b1 == 0xFFFFFFFFu){
    if (t == 0) wsf[8 + blockIdx.x] = 0.5f;   // cnt==0 -> sigma=1
    return;
  }
  unsigned n = cntg[isd ? 1 : 0];
  // scan m2 (16384 bins, 64 per thread)
  unsigned part = 0;
  for (int i = 0; i < 64; i++) part += m2[t*64 + i];
  sbuf[t] = part; __syncthreads();
  for (int off = 1; off < 256; off <<= 1){
    unsigned v = (t >= off) ? sbuf[t-off] : 0u; __syncthreads(); sbuf[t] += v; __syncthreads();
  }
  unsigned pre = sbuf[t] - part;
  __syncthreads();
  if (t == 0){ res[0] = 0u; res[1] = 0u; res[2] = 16u; }
  __syncthreads();
  if (k2 >= pre && k2 < pre + part){
    unsigned run = pre;
    for (int i = 0; i < 64; i++){
      unsigned c = m2[t*64 + i];
      if (k2 < run + c){ res[0] = (unsigned)(t*64 + i); res[1] = k2 - run; break; }
      run += c;
    }
  }
  __syncthreads();
  unsigned b2 = res[0], k3 = res[1];
  if (n <= CAP){
    if (t < 32) h32[t] = 0u;
    __syncthreads();
    unsigned n4 = n >> 2;
    const uint4* l4 = (const uint4*)list;
    for (unsigned i = t; i < n4; i += 256){
      uint4 v = l4[i];
      if ((v.x >> 5) == b2) atomicAdd(&h32[v.x & 31u], 1u);
      if ((v.y >> 5) == b2) atomicAdd(&h32[v.y & 31u], 1u);
      if ((v.z >> 5) == b2) atomicAdd(&h32[v.z & 31u], 1u);
      if ((v.w >> 5) == b2) atomicAdd(&h32[v.w & 31u], 1u);
    }
    for (unsigned i = n4*4 + t; i < n; i += 256){
      unsigned e = list[i];
      if ((e >> 5) == b2) atomicAdd(&h32[e & 31u], 1u);
    }
    __syncthreads();
    if (t == 0){
      unsigned run = 0;
      for (int i = 0; i < 32; i++){
        unsigned c = h32[i];
        if (k3 < run + c){ res[2] = (unsigned)i; break; }
        run += c;
      }
    }
    __syncthreads();
  }
  if (t == 0){
    unsigned med_bits = (b1 << 19) | (b2 << 5) | res[2];
    float med = __uint_as_float(med_bits);
    float sig = fmaxf(sqrtf(med), 1e-6f);
    wsf[8 + blockIdx.x] = 1.0f/(2.0f*sig*sig);
  }
}

// ---------------- HSIC accumulation pass (triangle) ----------------
__global__ __launch_bounds__(256,1) void k_hsic(const float* __restrict__ out,
    const float* __restrict__ xnc, const float* __restrict__ xnd,
    const float* __restrict__ wsf, double* __restrict__ wsd,
    float* __restrict__ rsc, float* __restrict__ rsd){
  __shared__ __align__(16) float ldsA[8192];
  __shared__ __align__(16) float ldsB[8192];
  int t = threadIdx.x;
  int bi, bj; tri_map(blockIdx.x, bi, bj);
  bool diag = (bi == bj);
  int i0 = bi*128, j0 = bj*128;
  int tx = t & 15, ty = t >> 4, tx8 = tx*8, ty8 = ty*8;
  float gc = wsf[8], gd = wsf[9];
  stageT<64>(out + O_ZC, ldsA, i0, t);
  stageT<64>(out + O_ZC, ldsB, j0, t);
  float xi[8], xj[8];
  #pragma unroll
  for (int ii = 0; ii < 8; ii++){ xi[ii] = xnc[i0+ty8+ii]; xj[ii] = xnc[j0+tx8+ii]; }
  __syncthreads();
  float kc[8][8] = {};
  dot8x8<64>(ldsA, ldsB, tx8, ty8, kc);
  #pragma unroll
  for (int ii = 0; ii < 8; ii++)
    #pragma unroll
    for (int jj = 0; jj < 8; jj++)
      kc[ii][jj] = __expf(-gc * fmaxf(xi[ii] + xj[jj] - 2.0f*kc[ii][jj], 0.0f));
  __syncthreads();
  stageT<16>(out + O_ZD, ldsA, i0, t);
  stageT<16>(out + O_ZD, ldsA + 2048, j0, t);
  #pragma unroll
  for (int ii = 0; ii < 8; ii++){ xi[ii] = xnd[i0+ty8+ii]; xj[ii] = xnd[j0+tx8+ii]; }
  __syncthreads();
  float ad[8][8] = {};
  dot8x8<16>(ldsA, ldsA + 2048, tx8, ty8, ad);
  float t1p = 0.0f;
  float rc[8] = {}, rd[8] = {}, cc[8] = {}, cd[8] = {};
  #pragma unroll
  for (int ii = 0; ii < 8; ii++)
    #pragma unroll
    for (int jj = 0; jj < 8; jj++){
      float kd = __expf(-gd * fmaxf(xi[ii] + xj[jj] - 2.0f*ad[ii][jj], 0.0f));
      float c = kc[ii][jj];
      t1p = fmaf(c, kd, t1p);
      rc[ii] += c; rd[ii] += kd;
      cc[jj] += c; cd[jj] += kd;
    }
  __syncthreads();
  float* red = ldsB;           // [0,128)rowC [128,256)rowD [256,384)colC [384,512)colD [512,516)t1
  red[t] = 0.0f; red[t + 256] = 0.0f;
  __syncthreads();
  #pragma unroll
  for (int ii = 0; ii < 8; ii++){
    atomicAdd(&red[ty8 + ii], rc[ii]);
    atomicAdd(&red[128 + ty8 + ii], rd[ii]);
  }
  if (!diag){
    #pragma unroll
    for (int jj = 0; jj < 8; jj++){
      atomicAdd(&red[256 + tx8 + jj], cc[jj]);
      atomicAdd(&red[384 + tx8 + jj], cd[jj]);
    }
  }
  #pragma unroll
  for (int off = 1; off < 64; off <<= 1) t1p += __shfl_xor(t1p, off);
  if ((t & 63) == 0) red[512 + (t >> 6)] = t1p;
  __syncthreads();
  if (t < 128){ atomicAdd(&rsc[i0 + t], red[t]); atomicAdd(&rsd[i0 + t], red[128 + t]); }
  else if (!diag){ atomicAdd(&rsc[j0 + t - 128], red[256 + t - 128]); atomicAdd(&rsd[j0 + t - 128], red[384 + t - 128]); }
  if (t == 0){
    double s = (double)red[512] + (double)red[513] + (double)red[514] + (double)red[515];
    if (!diag) s *= 2.0;
    atomicAdd(&wsd[0], s);
  }
}

// ---------------- final combine ----------------
__global__ __launch_bounds__(256) void k_combine(const double* __restrict__ wsd,
    const float* __restrict__ rsc, const float* __restrict__ rsd, float* __restrict__ dout){
  __shared__ double r1[256], r2[256], r3[256];
  int t = threadIdx.x;
  double sc = 0.0, sd = 0.0, pp = 0.0;
  for (int i = t; i < 4096; i += 256){
    double a = rsc[i], b = rsd[i];
    sc += a; sd += b; pp += a*b;
  }
  r1[t] = sc; r2[t] = sd; r3[t] = pp; __syncthreads();
  for (int off = 128; off > 0; off >>= 1){
    if (t < off){ r1[t] += r1[t+off]; r2[t] += r2[t+off]; r3[t] += r3[t+off]; }
    __syncthreads();
  }
  if (t == 0){
    double n = 4096.0;
    double T1 = wsd[0];
    double hs = (T1 - 2.0*r3[0]/n + r1[0]*r2[0]/(n*n)) / ((n-1.0)*(n-1.0));
    dout[O_HSIC] = (float)hs;
    dout[O_KL]   = (float)(-0.5 * wsd[1] / n);
  }
}

// ---------------- launcher ----------------
extern "C" void kernel_launch(void* const* d_in, const int* in_sizes, int n_in,
                              void* d_out, int out_size, void* d_ws, size_t ws_size,
                              hipStream_t stream){
  (void)in_sizes; (void)n_in; (void)out_size; (void)ws_size;
  const float* feat  = (const float*)d_in[0];
  const float* ln_g  = (const float*)d_in[1];
  const float* ln_b  = (const float*)d_in[2];
  const float* W_u   = (const float*)d_in[3];
  const float* b_u   = (const float*)d_in[4];
  const float* W1    = (const float*)d_in[5];
  const float* b1    = (const float*)d_in[6];
  const float* W2    = (const float*)d_in[7];
  const float* b2    = (const float*)d_in[8];
  const float* adj   = (const float*)d_in[9];
  const float* dln_g = (const float*)d_in[10];
  const float* dln_b = (const float*)d_in[11];
  const float* W_db  = (const float*)d_in[12];
  const float* b_db  = (const float*)d_in[13];
  const float* W_mu  = (const float*)d_in[14];
  const float* b_mu  = (const float*)d_in[15];
  const float* W_lv  = (const float*)d_in[16];
  const float* b_lv  = (const float*)d_in[17];
  const float* eps   = (const float*)d_in[18];
  float* out = (float*)d_out;
  char* ws = (char*)d_ws;
  float*  wsf = (float*)ws;
  double* wsd = (double*)ws;
  unsigned* cnt  = (unsigned*)(ws + WS_CNT);
  unsigned* h1c  = (unsigned*)(ws + WS_H1C);
  unsigned* h1d  = (unsigned*)(ws + WS_H1D);
  unsigned* m2c  = (unsigned*)(ws + WS_M2C);
  unsigned* m2d  = (unsigned*)(ws + WS_M2D);
  unsigned* listc= (unsigned*)(ws + WS_LISTC);
  unsigned* listd= (unsigned*)(ws + WS_LISTD);
  float* rsc  = (float*)(ws + WS_RSC);
  float* rsd  = (float*)(ws + WS_RSD);
  float* xnc  = (float*)(ws + WS_XNC);
  float* xnd  = (float*)(ws + WS_XND);
  float* Wc   = (float*)(ws + WS_WC);
  float* cst  = (float*)(ws + WS_CST);
  float* w1t0 = (float*)(ws + WS_W1T0);
  float* w1t1 = (float*)(ws + WS_W1T1);
  float* b1t  = (float*)(ws + WS_B1T);
  float* w2t  = (float*)(ws + WS_W2T);
  float* u_ws = (float*)(ws + WS_U);
  float* dh_ws= (float*)(ws + WS_DH);

  k_zero<<<dim3(64), dim3(256), 0, stream>>>((uint4*)ws, (int)(WS_ZEND/16u));
  k_prep<<<dim3(720), dim3(256), 0, stream>>>(ln_g, ln_b, W_u, b_u, dln_g, dln_b, W_db, b_db,
                                              adj, W1, b1, W2, Wc, cst, w1t0, w1t1, b1t, w2t,
                                              out + O_A);
  k_lngemm<<<dim3(256), dim3(512), 0, stream>>>(feat, Wc, cst, u_ws, dh_ws);
  k_causal<<<dim3(1024), dim3(256), 0, stream>>>(u_ws, out + O_A, w1t0, w1t1, b1t, w2t, b2,
                                                 out + O_ZC);
  k_domain<<<dim3(256), dim3(256), 0, stream>>>(dh_ws, W_mu, b_mu, W_lv, b_lv, eps, out, wsd);
  k_rownorm<<<dim3(1024), dim3(256), 0, stream>>>(out, xnc, xnd);
  k_pass1<<<dim3(529), dim3(256), 0, stream>>>(out, xnc, xnd, h1c, h1d, out);
  k_pass2<<<dim3(528), dim3(256), 0, stream>>>(out, xnc, xnd, h1c, h1d, m2c, m2d,
                                               listc, listd, cnt);
  k_scan2<<<dim3(2), dim3(256), 0, stream>>>(h1c, h1d, m2c, m2d, listc, listd, cnt, wsf);
  k_hsic<<<dim3(528), dim3(256), 0, stream>>>(out, xnc, xnd, wsf, wsd, rsc, rsd);
  k_combine<<<dim3(1), dim3(256), 0, stream>>>(wsd, rsc, rsd, out);
}

// Round 5
// 587.831 us; speedup vs baseline: 1.4844x; 1.4844x over previous
//
#include <hip/hip_runtime.h>
#include <math.h>

// ---------------- problem constants ----------------
#define NB 4096
#define ND 1024

// d_out float offsets
#define O_ZC   0
#define O_ZD   262144
#define O_MU   327680
#define O_LV   393216
#define O_A    458752
#define O_DAG  462848
#define O_HSIC 462849
#define O_KL   462850

// ws byte offsets (zeroed region: [0, WS_ZEND))
#define WS_H1C    256u
#define WS_H1D    33024u
#define WS_M2C    65792u
#define WS_M2D    73984u
#define WS_RSC    82176u
#define WS_RSD    98560u
#define WS_ZEND   114944u
// non-zeroed scratch
#define WS_XNC    114944u
#define WS_XND    131328u
#define WS_WC     147712u
#define WS_CST    672000u
#define WS_W1T0   672512u
#define WS_W1T1   688896u
#define WS_B1T    705280u
#define WS_W2T    721664u
#define WS_U      738048u
#define WS_DH     1786624u

// fast erf-based gelu: A&S 7.1.26, |err| <= 1.5e-7, branch-free
__device__ __forceinline__ float gelu_f(float x){
  float y = fabsf(x) * 0.70710678118654752440f;
  float t = 1.0f / (1.0f + 0.3275911f * y);
  float poly = t*(0.254829592f + t*(-0.284496736f + t*(1.421413741f + t*(-1.453152027f + t*1.061405429f))));
  float e = __expf(-y*y);
  float er = 1.0f - poly*e;
  float s = copysignf(er, x);
  return 0.5f * x * (1.0f + s);
}

// triangle block map: b -> (bi <= bj), b = bj*(bj+1)/2 + bi
__device__ __forceinline__ void tri_map(int b, int& bi, int& bj){
  int r = (int)((sqrtf(8.0f*(float)b + 1.0f) - 1.0f) * 0.5f);
  while ((r+1)*(r+2)/2 <= b) r++;
  while (r*(r+1)/2 > b) r--;
  bj = r; bi = b - r*(r+1)/2;
}

// packed (u64) staggered histogram flush: hist has 2*n2 u32 bins, g is u64[n2]
// per-block counts < 2^32 and global totals < 2^32 -> no carry across halves
__device__ __forceinline__ void flush_hist(const unsigned* __restrict__ hist,
                                           unsigned long long* __restrict__ g,
                                           int n2, int t, int salt){
  for (int e = t; e < n2; e += 256){
    int idx = (e + salt) & (n2 - 1);
    unsigned lo = hist[2*idx], hi = hist[2*idx + 1];
    if (lo | hi)
      atomicAdd(&g[idx], (unsigned long long)lo | ((unsigned long long)hi << 32));
  }
}

// ---------------- zero scratch ----------------
__global__ __launch_bounds__(256) void k_zero(uint4* p, int n){
  uint4 z; z.x = 0; z.y = 0; z.z = 0; z.w = 0;
  for (int i = blockIdx.x*256 + threadIdx.x; i < n; i += gridDim.x*256) p[i] = z;
}

// ---------------- prep: folded weights, A, consts, causal transposes ----------------
__global__ __launch_bounds__(256) void k_prep(
    const float* __restrict__ ln_g, const float* __restrict__ ln_b,
    const float* __restrict__ W_u,  const float* __restrict__ b_u,
    const float* __restrict__ dln_g,const float* __restrict__ dln_b,
    const float* __restrict__ W_db, const float* __restrict__ b_db,
    const float* __restrict__ adj,  const float* __restrict__ W1,
    const float* __restrict__ b1,   const float* __restrict__ W2,
    float* __restrict__ Wc, float* __restrict__ cst,
    float* __restrict__ w1t0, float* __restrict__ w1t1,
    float* __restrict__ b1t,  float* __restrict__ w2t,
    float* __restrict__ outA){
  __shared__ float red[256];
  int t = threadIdx.x, b = blockIdx.x;
  if (b < 512){
    int e = b*256 + t; int c = e & 127, d = e >> 7;
    Wc[e] = (c < 64) ? ln_g[d]*W_u[d*64 + c] : dln_g[d]*W_db[d*64 + (c-64)];
  } else if (b < 528){
    int e = (b-512)*256 + t; int i = e >> 6, j = e & 63;
    float a = 1.0f/(1.0f + __expf(-adj[e]));
    outA[e] = (i == j) ? 0.0f : a;
  } else if (b < 656){
    int col = b - 528;
    float p = 0.0f;
    for (int d = t; d < 1024; d += 256)
      p += (col < 64) ? ln_b[d]*W_u[d*64 + col] : dln_b[d]*W_db[d*64 + (col-64)];
    red[t] = p; __syncthreads();
    for (int off = 128; off > 0; off >>= 1){ if (t < off) red[t] += red[t+off]; __syncthreads(); }
    if (t == 0) cst[col] = red[0] + ((col < 64) ? b_u[col] : b_db[col-64]);
  } else {
    int e = (b-656)*256 + t; int which = e >> 12, r = e & 4095;
    int j = r >> 6, k = r & 63;
    if (which == 0)      w1t0[j*64+k] = W1[k*128 + j];
    else if (which == 1) w1t1[j*64+k] = W1[k*128 + 64 + j];
    else if (which == 2) b1t [j*64+k] = b1[k*64 + j];
    else                 w2t [j*64+k] = W2[k*64 + j];
  }
}

// ---------------- LN + dual GEMM (u pre-bias, dh pre-gelu) ----------------
__global__ __launch_bounds__(512) void k_lngemm(const float* __restrict__ feat,
    const float* __restrict__ Wc, const float* __restrict__ cst,
    float* __restrict__ u_ws, float* __restrict__ dh_ws){
  __shared__ float xh[16][1024];   // 64KB
  int t = threadIdx.x, b = blockIdx.x;
  {
    int row = t >> 5, lane = t & 31;
    const float4* src = (const float4*)(feat + (b*16 + row)*1024);
    float4 v[8]; float s = 0.0f, s2 = 0.0f;
    #pragma unroll
    for (int q = 0; q < 8; q++){
      v[q] = src[lane + q*32];
      s += v[q].x + v[q].y + v[q].z + v[q].w;
      s2 = fmaf(v[q].x,v[q].x, fmaf(v[q].y,v[q].y, fmaf(v[q].z,v[q].z, fmaf(v[q].w,v[q].w, s2))));
    }
    #pragma unroll
    for (int off = 1; off < 32; off <<= 1){ s += __shfl_xor(s, off); s2 += __shfl_xor(s2, off); }
    float mean = s * (1.0f/1024.0f);
    float var  = s2 * (1.0f/1024.0f) - mean*mean;
    float rs = rsqrtf(var + 1e-5f);
    float4* dst = (float4*)&xh[row][0];
    #pragma unroll
    for (int q = 0; q < 8; q++){
      float4 w; w.x = (v[q].x-mean)*rs; w.y = (v[q].y-mean)*rs;
      w.z = (v[q].z-mean)*rs; w.w = (v[q].w-mean)*rs;
      dst[lane + q*32] = w;
    }
  }
  __syncthreads();
  int col = t & 127, rg = t >> 7;    // rg in [0,4): 4 rows each
  float acc[4] = {0,0,0,0};
  for (int d0 = 0; d0 < 1024; d0 += 4){
    float w0 = Wc[(d0  )*128 + col];
    float w1 = Wc[(d0+1)*128 + col];
    float w2 = Wc[(d0+2)*128 + col];
    float w3 = Wc[(d0+3)*128 + col];
    #pragma unroll
    for (int r = 0; r < 4; r++){
      float4 x = *(const float4*)&xh[rg*4 + r][d0];
      acc[r] = fmaf(x.x,w0, fmaf(x.y,w1, fmaf(x.z,w2, fmaf(x.w,w3, acc[r]))));
    }
  }
  float cc = cst[col];
  #pragma unroll
  for (int r = 0; r < 4; r++){
    int grow = b*16 + rg*4 + r;
    float o = acc[r] + cc;
    if (col < 64) u_ws[grow*64 + col] = o;
    else          dh_ws[grow*64 + (col-64)] = o;
  }
}

// ---------------- causal structural loop (wave per row) ----------------
__global__ __launch_bounds__(256) void k_causal(const float* __restrict__ u_ws,
    const float* __restrict__ A_g, const float* __restrict__ w1t0g, const float* __restrict__ w1t1g,
    const float* __restrict__ b1tg, const float* __restrict__ w2tg, const float* __restrict__ b2_g,
    float* __restrict__ zc_out){
  __shared__ float w1t0[4096], w1t1[4096];
  __shared__ float zbuf[4][64];
  int t = threadIdx.x;
  for (int e = t; e < 4096; e += 256){ w1t0[e] = w1t0g[e]; w1t1[e] = w1t1g[e]; }
  int w = t >> 6, k = t & 63;
  int row = blockIdx.x*4 + w;
  float uu = u_ws[row*64 + k];
  float b2v = b2_g[k];
  float z = uu;
  __syncthreads();
  #pragma unroll
  for (int itr = 0; itr < 2; ++itr){
    zbuf[w][k] = z;
    float p0=0.f,p1=0.f,p2=0.f,p3=0.f;
    #pragma unroll
    for (int j0 = 0; j0 < 64; j0 += 4){
      float4 zz = *(const float4*)&zbuf[w][j0];
      p0 = fmaf(zz.x, A_g[(j0+0)*64 + k], p0);
      p1 = fmaf(zz.y, A_g[(j0+1)*64 + k], p1);
      p2 = fmaf(zz.z, A_g[(j0+2)*64 + k], p2);
      p3 = fmaf(zz.w, A_g[(j0+3)*64 + k], p3);
    }
    float p = (p0+p1)+(p2+p3);
    float a0=0.f, a1=0.f;
    #pragma unroll 8
    for (int j = 0; j < 64; j += 2){
      float pre0 = fmaf(p, w1t0[j*64+k],     fmaf(uu, w1t1[j*64+k],     b1tg[j*64+k]));
      float pre1 = fmaf(p, w1t0[(j+1)*64+k], fmaf(uu, w1t1[(j+1)*64+k], b1tg[(j+1)*64+k]));
      a0 = fmaf(gelu_f(pre0), w2tg[j*64+k],     a0);
      a1 = fmaf(gelu_f(pre1), w2tg[(j+1)*64+k], a1);
    }
    z = a0 + a1 + b2v;
  }
  zc_out[row*64 + k] = z;
}

// ---------------- domain head: gelu, mu/lv, z_d, KL ----------------
__global__ __launch_bounds__(256) void k_domain(const float* __restrict__ dh_ws,
    const float* __restrict__ Wmu, const float* __restrict__ bmu,
    const float* __restrict__ Wlv, const float* __restrict__ blv,
    const float* __restrict__ eps, float* __restrict__ out, double* __restrict__ wsd){
  __shared__ float hb[4][64];
  int t = threadIdx.x, w = t >> 6, l = t & 63;
  int dd = l & 15;
  double klacc = 0.0;
  for (int it = 0; it < 4; ++it){
    int row = blockIdx.x*16 + it*4 + w;
    hb[w][l] = gelu_f(dh_ws[row*64 + l]);
    float val = 0.0f;
    if (l < 32){
      const float* W = (l < 16) ? Wmu : Wlv;
      float a = (l < 16) ? bmu[dd] : blv[dd];
      for (int j = 0; j < 64; j++) a = fmaf(hb[w][j], W[j*16 + dd], a);
      val = a;
    }
    float mu = __shfl(val, dd);
    float lv = __shfl(val, 16 + dd);
    float kle = 0.0f;
    if (l < 16){
      out[O_MU + row*16 + dd] = mu;
      out[O_LV + row*16 + dd] = lv;
      out[O_ZD + row*16 + dd] = fmaf(eps[row*16 + dd], __expf(0.5f*lv), mu);
      kle = 1.0f + lv - mu*mu - __expf(lv);
    }
    #pragma unroll
    for (int off = 1; off < 16; off <<= 1) kle += __shfl_xor(kle, off);
    if (l == 0) klacc += (double)kle;
  }
  if (l == 0) atomicAdd(&wsd[1], klacc);
}

// ---------------- row squared norms ----------------
__global__ __launch_bounds__(256) void k_rownorm(const float* __restrict__ out,
    float* __restrict__ xnc, float* __restrict__ xnd){
  int t = threadIdx.x, w = t >> 6, l = t & 63;
  int row = blockIdx.x*4 + w;
  float zc = out[O_ZC + row*64 + l];
  float a = zc*zc;
  #pragma unroll
  for (int off = 1; off < 64; off <<= 1) a += __shfl_xor(a, off);
  if (l == 0) xnc[row] = a;
  float zd = (l < 16) ? out[O_ZD + row*16 + l] : 0.0f;
  float bs = zd*zd;
  #pragma unroll
  for (int off = 1; off < 16; off <<= 1) bs += __shfl_xor(bs, off);
  if (l == 0) xnd[row] = bs;
}

// ---------------- tile staging + 8x8 dot micro-kernel ----------------
template<int DIM>
__device__ __forceinline__ void stageT(const float* __restrict__ src, float* __restrict__ dst,
                                       int i0, int t){
  for (int e = t; e < DIM*128; e += 256){
    int k = e & (DIM-1);
    int r = e >> (DIM == 64 ? 6 : 4);
    dst[k*128 + (r ^ ((k & 7) << 2))] = src[(i0 + r)*DIM + k];
  }
}

template<int KDIM>
__device__ __forceinline__ void dot8x8(const float* __restrict__ LA, const float* __restrict__ LB,
                                       int tx8, int ty8, float acc[8][8]){
  #pragma unroll 8
  for (int k = 0; k < KDIM; k++){
    int s = (k & 7) << 2;
    const float* pa = LA + k*128;
    const float* pb = LB + k*128;
    float4 a0 = *(const float4*)(pa + ((ty8    ) ^ s));
    float4 a1 = *(const float4*)(pa + ((ty8 + 4) ^ s));
    float4 b0 = *(const float4*)(pb + ((tx8    ) ^ s));
    float4 b1 = *(const float4*)(pb + ((tx8 + 4) ^ s));
    float av[8] = {a0.x,a0.y,a0.z,a0.w,a1.x,a1.y,a1.z,a1.w};
    float bv[8] = {b0.x,b0.y,b0.z,b0.w,b1.x,b1.y,b1.z,b1.w};
    #pragma unroll
    for (int ii = 0; ii < 8; ii++)
      #pragma unroll
      for (int jj = 0; jj < 8; jj++)
        acc[ii][jj] = fmaf(av[ii], bv[jj], acc[ii][jj]);
  }
}

// ---------------- dag: expm via scaling & squaring (single block) ----------------
__device__ void dag_mm(float* __restrict__ C, const float* __restrict__ Am, const float* __restrict__ Bm,
                       const float* __restrict__ Xm, float cI, float cX, int t, bool addG){
  int tx = t & 15, ty = t >> 4;
  float acc[4][4] = {};
  for (int k0 = 0; k0 < 64; k0 += 4){
    float4 a0 = *(const float4*)&Am[(ty*4+0)*64 + k0];
    float4 a1 = *(const float4*)&Am[(ty*4+1)*64 + k0];
    float4 a2 = *(const float4*)&Am[(ty*4+2)*64 + k0];
    float4 a3 = *(const float4*)&Am[(ty*4+3)*64 + k0];
    float4 b0 = *(const float4*)&Bm[(k0+0)*64 + tx*4];
    float4 b1 = *(const float4*)&Bm[(k0+1)*64 + tx*4];
    float4 b2 = *(const float4*)&Bm[(k0+2)*64 + tx*4];
    float4 b3 = *(const float4*)&Bm[(k0+3)*64 + tx*4];
#define MQ(ii, AV) \
    acc[ii][0] = fmaf(AV.x,b0.x, fmaf(AV.y,b1.x, fmaf(AV.z,b2.x, fmaf(AV.w,b3.x, acc[ii][0])))); \
    acc[ii][1] = fmaf(AV.x,b0.y, fmaf(AV.y,b1.y, fmaf(AV.z,b2.y, fmaf(AV.w,b3.y, acc[ii][1])))); \
    acc[ii][2] = fmaf(AV.x,b0.z, fmaf(AV.y,b1.z, fmaf(AV.z,b2.z, fmaf(AV.w,b3.z, acc[ii][2])))); \
    acc[ii][3] = fmaf(AV.x,b0.w, fmaf(AV.y,b1.w, fmaf(AV.z,b2.w, fmaf(AV.w,b3.w, acc[ii][3]))));
    MQ(0,a0) MQ(1,a1) MQ(2,a2) MQ(3,a3)
#undef MQ
  }
  #pragma unroll
  for (int ii = 0; ii < 4; ii++)
    #pragma unroll
    for (int jj = 0; jj < 4; jj++){
      int i = ty*4 + ii, j = tx*4 + jj;
      float v = acc[ii][jj];
      if (addG) v += ((i == j) ? cI : 0.0f) + cX * Xm[i*64 + j];
      C[i*64 + j] = v;
    }
  __syncthreads();
}

__device__ void dag_expm(float* ldsA, float* ldsB, const float* __restrict__ A_g,
                         float* __restrict__ dout){
  int t = threadIdx.x;
  float* X  = ldsA;
  float* X2 = ldsA + 4096;
  float* P  = ldsB;
  float* Pn = ldsB + 4096;
  for (int e = t; e < 4096; e += 256){ float a = A_g[e]; X[e] = a*a; }
  __syncthreads();
  int l = t & 63;
  float cs = 0.0f;
  for (int i = 0; i < 64; i++) cs += X[i*64 + l];
  #pragma unroll
  for (int off = 1; off < 64; off <<= 1) cs = fmaxf(cs, __shfl_xor(cs, off));
  int s_ = 0;
  if (cs > 2.0f) s_ = (int)ceilf(log2f(cs * 0.5f));
  if (s_ < 0) s_ = 0; if (s_ > 12) s_ = 12;
  float sc = exp2f((float)(-s_));
  __syncthreads();
  for (int e = t; e < 4096; e += 256) X[e] *= sc;
  __syncthreads();
  dag_mm(X2, X, X, X, 0.0f, 0.0f, t, false);
  const float C12 = 2.0876756987868099e-9f, C13 = 1.6059043836821613e-10f;
  for (int e = t; e < 4096; e += 256){
    int i = e >> 6, j = e & 63;
    P[e] = C13*X[e] + ((i == j) ? C12 : 0.0f);
  }
  __syncthreads();
  const float cf[12] = {1.0f, 1.0f, 0.5f, 1.0f/6.0f, 1.0f/24.0f, 1.0f/120.0f,
                        1.0f/720.0f, 1.0f/5040.0f, 1.0f/40320.0f, 1.0f/362880.0f,
                        1.0f/3628800.0f, 1.0f/39916800.0f};
  #pragma unroll
  for (int g = 5; g >= 0; --g){
    dag_mm(Pn, X2, P, X, cf[2*g], cf[2*g+1], t, true);
    float* tmp = P; P = Pn; Pn = tmp;
  }
  for (int q = 0; q < s_; ++q){
    dag_mm(Pn, P, P, X, 0.0f, 0.0f, t, false);
    float* tmp = P; P = Pn; Pn = tmp;
  }
  if (t < 64){
    float tr = P[t*65];
    #pragma unroll
    for (int off = 1; off < 64; off <<= 1) tr += __shfl_xor(tr, off);
    if (t == 0) dout[O_DAG] = tr - 64.0f;
  }
}

// ---------------- median pass 1: top-13-bit histograms, triangle (+dag block) ----------------
__global__ __launch_bounds__(256,1) void k_pass1(const float* __restrict__ out,
    const float* __restrict__ xnc, const float* __restrict__ xnd,
    unsigned long long* __restrict__ h1c, unsigned long long* __restrict__ h1d,
    float* __restrict__ dout){
  __shared__ __align__(16) float ldsA[8192];
  __shared__ __align__(16) float ldsB[8192];
  int t = threadIdx.x;
  if (blockIdx.x == 528){ dag_expm(ldsA, ldsB, out + O_A, dout); return; }
  int bi, bj; tri_map(blockIdx.x, bi, bj);
  bool diag = (bi == bj);
  int i0 = bi*128, j0 = bj*128;
  int tx = t & 15, ty = t >> 4, tx8 = tx*8, ty8 = ty*8;
  stageT<64>(out + O_ZC, ldsA, i0, t);
  stageT<64>(out + O_ZC, ldsB, j0, t);
  float xi[8], xj[8];
  #pragma unroll
  for (int ii = 0; ii < 8; ii++){ xi[ii] = xnc[i0+ty8+ii]; xj[ii] = xnc[j0+tx8+ii]; }
  __syncthreads();
  float acc[8][8] = {};
  dot8x8<64>(ldsA, ldsB, tx8, ty8, acc);
  __syncthreads();
  unsigned* hist = (unsigned*)ldsA;
  for (int e = t; e < 8192; e += 256) hist[e] = 0u;
  __syncthreads();
  #pragma unroll
  for (int ii = 0; ii < 8; ii++)
    #pragma unroll
    for (int jj = 0; jj < 8; jj++){
      float d2 = xi[ii] + xj[jj] - 2.0f*acc[ii][jj];
      bool take = diag ? ((i0+ty8+ii) < (j0+tx8+jj)) : true;
      if (take && d2 > 0.0f)
        atomicAdd(&hist[__float_as_uint(d2) >> 19], 1u);
    }
  __syncthreads();
  flush_hist(hist, h1c, 4096, t, blockIdx.x * 37);
  __syncthreads();
  // d phase
  stageT<16>(out + O_ZD, ldsB, i0, t);
  stageT<16>(out + O_ZD, ldsB + 2048, j0, t);
  #pragma unroll
  for (int ii = 0; ii < 8; ii++){ xi[ii] = xnd[i0+ty8+ii]; xj[ii] = xnd[j0+tx8+ii]; }
  __syncthreads();
  float acd[8][8] = {};
  dot8x8<16>(ldsB, ldsB + 2048, tx8, ty8, acd);
  __syncthreads();
  for (int e = t; e < 8192; e += 256) hist[e] = 0u;
  __syncthreads();
  #pragma unroll
  for (int ii = 0; ii < 8; ii++)
    #pragma unroll
    for (int jj = 0; jj < 8; jj++){
      float d2 = xi[ii] + xj[jj] - 2.0f*acd[ii][jj];
      bool take = diag ? ((i0+ty8+ii) < (j0+tx8+jj)) : true;
      if (take && d2 > 0.0f)
        atomicAdd(&hist[__float_as_uint(d2) >> 19], 1u);
    }
  __syncthreads();
  flush_hist(hist, h1d, 4096, t, blockIdx.x * 53);
}

// find target bin (and rank within bin) from a level-1 histogram; counts once per pair
__device__ unsigned find_bin(const unsigned* __restrict__ h1, unsigned* sbuf, int t, unsigned* k2out){
  unsigned part = 0;
  for (int i = 0; i < 32; i++) part += h1[t*32 + i];
  sbuf[t] = part;
  __syncthreads();
  for (int off = 1; off < 256; off <<= 1){
    unsigned v = (t >= off) ? sbuf[t-off] : 0u;
    __syncthreads();
    sbuf[t] += v;
    __syncthreads();
  }
  unsigned total = sbuf[255];
  unsigned pre = sbuf[t] - part;
  __syncthreads();
  if (t == 0){ sbuf[0] = 0xFFFFFFFFu; sbuf[1] = 0u; }
  __syncthreads();
  if (total > 0){
    unsigned rt = (total - 1u) >> 1;   // lower median rank
    if (rt >= pre && rt < pre + part){
      unsigned run = pre;
      for (int i = 0; i < 32; i++){
        unsigned c = h1[t*32 + i];
        if (rt < run + c){ sbuf[0] = (unsigned)(t*32 + i); sbuf[1] = rt - run; break; }
        run += c;
      }
    }
  }
  __syncthreads();
  unsigned b1 = sbuf[0];
  unsigned k2 = sbuf[1];
  __syncthreads();
  if (k2out) *k2out = k2;
  return b1;
}

// ---------------- median pass 2: LDS 2048-bin mid hist (bits 18:8) ----------------
__global__ __launch_bounds__(256,1) void k_pass2(const float* __restrict__ out,
    const float* __restrict__ xnc, const float* __restrict__ xnd,
    const unsigned* __restrict__ h1c, const unsigned* __restrict__ h1d,
    unsigned long long* __restrict__ m2c, unsigned long long* __restrict__ m2d){
  __shared__ __align__(16) float ldsA[8192];
  __shared__ __align__(16) float ldsB[8192];
  unsigned* hist = (unsigned*)ldsA;            // 2048 bins, reused after dots
  int t = threadIdx.x;
  unsigned b1c = find_bin(h1c, (unsigned*)ldsA, t, nullptr);
  unsigned b1d = find_bin(h1d, (unsigned*)ldsA, t, nullptr);
  int bi, bj; tri_map(blockIdx.x, bi, bj);
  bool diag = (bi == bj);
  int i0 = bi*128, j0 = bj*128;
  int tx = t & 15, ty = t >> 4, tx8 = tx*8, ty8 = ty*8;
  // ---- c phase ----
  stageT<64>(out + O_ZC, ldsA, i0, t);
  stageT<64>(out + O_ZC, ldsB, j0, t);
  float xi[8], xj[8];
  #pragma unroll
  for (int ii = 0; ii < 8; ii++){ xi[ii] = xnc[i0+ty8+ii]; xj[ii] = xnc[j0+tx8+ii]; }
  __syncthreads();
  float acc[8][8] = {};
  dot8x8<64>(ldsA, ldsB, tx8, ty8, acc);
  __syncthreads();
  for (int e = t; e < 2048; e += 256) hist[e] = 0u;
  __syncthreads();
  #pragma unroll
  for (int ii = 0; ii < 8; ii++)
    #pragma unroll
    for (int jj = 0; jj < 8; jj++){
      float d2 = xi[ii] + xj[jj] - 2.0f*acc[ii][jj];
      unsigned u = __float_as_uint(d2);
      bool take = (diag ? ((i0+ty8+ii) < (j0+tx8+jj)) : true) && d2 > 0.0f && (u >> 19) == b1c;
      if (take) atomicAdd(&hist[(u >> 8) & 0x7FFu], 1u);
    }
  __syncthreads();
  flush_hist(hist, m2c, 1024, t, blockIdx.x * 37);
  __syncthreads();
  // ---- d phase ----
  stageT<16>(out + O_ZD, ldsB, i0, t);
  stageT<16>(out + O_ZD, ldsB + 2048, j0, t);
  #pragma unroll
  for (int ii = 0; ii < 8; ii++){ xi[ii] = xnd[i0+ty8+ii]; xj[ii] = xnd[j0+tx8+ii]; }
  __syncthreads();
  float acd[8][8] = {};
  dot8x8<16>(ldsB, ldsB + 2048, tx8, ty8, acd);
  __syncthreads();
  for (int e = t; e < 2048; e += 256) hist[e] = 0u;
  __syncthreads();
  #pragma unroll
  for (int ii = 0; ii < 8; ii++)
    #pragma unroll
    for (int jj = 0; jj < 8; jj++){
      float d2 = xi[ii] + xj[jj] - 2.0f*acd[ii][jj];
      unsigned u = __float_as_uint(d2);
      bool take = (diag ? ((i0+ty8+ii) < (j0+tx8+jj)) : true) && d2 > 0.0f && (u >> 19) == b1d;
      if (take) atomicAdd(&hist[(u >> 8) & 0x7FFu], 1u);
    }
  __syncthreads();
  flush_hist(hist, m2d, 1024, t, blockIdx.x * 53);
}

// ---------------- median finalize: m2 scan (bits 18:8) -> midpoint -> gamma ----------------
__global__ __launch_bounds__(256) void k_scan2(const unsigned* __restrict__ h1c,
    const unsigned* __restrict__ h1d, const unsigned* __restrict__ m2c,
    const unsigned* __restrict__ m2d, float* __restrict__ wsf){
  __shared__ unsigned sbuf[256];
  __shared__ unsigned res[2];
  int t = threadIdx.x;
  bool isd = blockIdx.x != 0;
  const unsigned* h1 = isd ? h1d : h1c;
  const unsigned* m2 = isd ? m2d : m2c;
  unsigned k2;
  unsigned b1 = find_bin(h1, sbuf, t, &k2);
  if (b1 == 0xFFFFFFFFu){
    if (t == 0) wsf[8 + blockIdx.x] = 0.5f;   // cnt==0 -> sigma=1
    return;
  }
  // scan m2 (2048 bins, 8 per thread)
  unsigned part = 0;
  #pragma unroll
  for (int i = 0; i < 8; i++) part += m2[t*8 + i];
  sbuf[t] = part; __syncthreads();
  for (int off = 1; off < 256; off <<= 1){
    unsigned v = (t >= off) ? sbuf[t-off] : 0u; __syncthreads(); sbuf[t] += v; __syncthreads();
  }
  unsigned pre = sbuf[t] - part;
  __syncthreads();
  if (t == 0) res[0] = 0u;
  __syncthreads();
  if (k2 >= pre && k2 < pre + part){
    unsigned run = pre;
    #pragma unroll
    for (int i = 0; i < 8; i++){
      unsigned c = m2[t*8 + i];
      if (k2 < run + c){ res[0] = (unsigned)(t*8 + i); break; }
      run += c;
    }
  }
  __syncthreads();
  if (t == 0){
    unsigned med_bits = (b1 << 19) | (res[0] << 8) | 128u;   // bin midpoint (rel err ~1.5e-5)
    float med = __uint_as_float(med_bits);
    float sig = fmaxf(sqrtf(med), 1e-6f);
    wsf[8 + blockIdx.x] = 1.0f/(2.0f*sig*sig);
  }
}

// ---------------- HSIC accumulation pass (triangle) ----------------
__global__ __launch_bounds__(256,1) void k_hsic(const float* __restrict__ out,
    const float* __restrict__ xnc, const float* __restrict__ xnd,
    const float* __restrict__ wsf, double* __restrict__ wsd,
    float* __restrict__ rsc, float* __restrict__ rsd){
  __shared__ __align__(16) float ldsA[8192];
  __shared__ __align__(16) float ldsB[8192];
  int t = threadIdx.x;
  int bi, bj; tri_map(blockIdx.x, bi, bj);
  bool diag = (bi == bj);
  int i0 = bi*128, j0 = bj*128;
  int tx = t & 15, ty = t >> 4, tx8 = tx*8, ty8 = ty*8;
  float gc = wsf[8], gd = wsf[9];
  stageT<64>(out + O_ZC, ldsA, i0, t);
  stageT<64>(out + O_ZC, ldsB, j0, t);
  float xi[8], xj[8];
  #pragma unroll
  for (int ii = 0; ii < 8; ii++){ xi[ii] = xnc[i0+ty8+ii]; xj[ii] = xnc[j0+tx8+ii]; }
  __syncthreads();
  float kc[8][8] = {};
  dot8x8<64>(ldsA, ldsB, tx8, ty8, kc);
  #pragma unroll
  for (int ii = 0; ii < 8; ii++)
    #pragma unroll
    for (int jj = 0; jj < 8; jj++)
      kc[ii][jj] = __expf(-gc * fmaxf(xi[ii] + xj[jj] - 2.0f*kc[ii][jj], 0.0f));
  __syncthreads();
  stageT<16>(out + O_ZD, ldsA, i0, t);
  stageT<16>(out + O_ZD, ldsA + 2048, j0, t);
  #pragma unroll
  for (int ii = 0; ii < 8; ii++){ xi[ii] = xnd[i0+ty8+ii]; xj[ii] = xnd[j0+tx8+ii]; }
  __syncthreads();
  float ad[8][8] = {};
  dot8x8<16>(ldsA, ldsA + 2048, tx8, ty8, ad);
  float t1p = 0.0f;
  float rc[8] = {}, rd[8] = {}, cc[8] = {}, cd[8] = {};
  #pragma unroll
  for (int ii = 0; ii < 8; ii++)
    #pragma unroll
    for (int jj = 0; jj < 8; jj++){
      float kd = __expf(-gd * fmaxf(xi[ii] + xj[jj] - 2.0f*ad[ii][jj], 0.0f));
      float c = kc[ii][jj];
      t1p = fmaf(c, kd, t1p);
      rc[ii] += c; rd[ii] += kd;
      cc[jj] += c; cd[jj] += kd;
    }
  __syncthreads();
  float* red = ldsB;           // [0,128)rowC [128,256)rowD [256,384)colC [384,512)colD [512,516)t1
  red[t] = 0.0f; red[t + 256] = 0.0f;
  __syncthreads();
  #pragma unroll
  for (int ii = 0; ii < 8; ii++){
    atomicAdd(&red[ty8 + ii], rc[ii]);
    atomicAdd(&red[128 + ty8 + ii], rd[ii]);
  }
  if (!diag){
    #pragma unroll
    for (int jj = 0; jj < 8; jj++){
      atomicAdd(&red[256 + tx8 + jj], cc[jj]);
      atomicAdd(&red[384 + tx8 + jj], cd[jj]);
    }
  }
  #pragma unroll
  for (int off = 1; off < 64; off <<= 1) t1p += __shfl_xor(t1p, off);
  if ((t & 63) == 0) red[512 + (t >> 6)] = t1p;
  __syncthreads();
  if (t < 128){ atomicAdd(&rsc[i0 + t], red[t]); atomicAdd(&rsd[i0 + t], red[128 + t]); }
  else if (!diag){ atomicAdd(&rsc[j0 + t - 128], red[256 + t - 128]); atomicAdd(&rsd[j0 + t - 128], red[384 + t - 128]); }
  if (t == 0){
    double s = (double)red[512] + (double)red[513] + (double)red[514] + (double)red[515];
    if (!diag) s *= 2.0;
    atomicAdd(&wsd[0], s);
  }
}

// ---------------- final combine ----------------
__global__ __launch_bounds__(256) void k_combine(const double* __restrict__ wsd,
    const float* __restrict__ rsc, const float* __restrict__ rsd, float* __restrict__ dout){
  __shared__ double r1[256], r2[256], r3[256];
  int t = threadIdx.x;
  double sc = 0.0, sd = 0.0, pp = 0.0;
  for (int i = t; i < 4096; i += 256){
    double a = rsc[i], b = rsd[i];
    sc += a; sd += b; pp += a*b;
  }
  r1[t] = sc; r2[t] = sd; r3[t] = pp; __syncthreads();
  for (int off = 128; off > 0; off >>= 1){
    if (t < off){ r1[t] += r1[t+off]; r2[t] += r2[t+off]; r3[t] += r3[t+off]; }
    __syncthreads();
  }
  if (t == 0){
    double n = 4096.0;
    double T1 = wsd[0];
    double hs = (T1 - 2.0*r3[0]/n + r1[0]*r2[0]/(n*n)) / ((n-1.0)*(n-1.0));
    dout[O_HSIC] = (float)hs;
    dout[O_KL]   = (float)(-0.5 * wsd[1] / n);
  }
}

// ---------------- launcher ----------------
extern "C" void kernel_launch(void* const* d_in, const int* in_sizes, int n_in,
                              void* d_out, int out_size, void* d_ws, size_t ws_size,
                              hipStream_t stream){
  (void)in_sizes; (void)n_in; (void)out_size; (void)ws_size;
  const float* feat  = (const float*)d_in[0];
  const float* ln_g  = (const float*)d_in[1];
  const float* ln_b  = (const float*)d_in[2];
  const float* W_u   = (const float*)d_in[3];
  const float* b_u   = (const float*)d_in[4];
  const float* W1    = (const float*)d_in[5];
  const float* b1    = (const float*)d_in[6];
  const float* W2    = (const float*)d_in[7];
  const float* b2    = (const float*)d_in[8];
  const float* adj   = (const float*)d_in[9];
  const float* dln_g = (const float*)d_in[10];
  const float* dln_b = (const float*)d_in[11];
  const float* W_db  = (const float*)d_in[12];
  const float* b_db  = (const float*)d_in[13];
  const float* W_mu  = (const float*)d_in[14];
  const float* b_mu  = (const float*)d_in[15];
  const float* W_lv  = (const float*)d_in[16];
  const float* b_lv  = (const float*)d_in[17];
  const float* eps   = (const float*)d_in[18];
  float* out = (float*)d_out;
  char* ws = (char*)d_ws;
  float*  wsf = (float*)ws;
  double* wsd = (double*)ws;
  unsigned* h1c  = (unsigned*)(ws + WS_H1C);
  unsigned* h1d  = (unsigned*)(ws + WS_H1D);
  unsigned* m2c  = (unsigned*)(ws + WS_M2C);
  unsigned* m2d  = (unsigned*)(ws + WS_M2D);
  float* rsc  = (float*)(ws + WS_RSC);
  float* rsd  = (float*)(ws + WS_RSD);
  float* xnc  = (float*)(ws + WS_XNC);
  float* xnd  = (float*)(ws + WS_XND);
  float* Wc   = (float*)(ws + WS_WC);
  float* cst  = (float*)(ws + WS_CST);
  float* w1t0 = (float*)(ws + WS_W1T0);
  float* w1t1 = (float*)(ws + WS_W1T1);
  float* b1t  = (float*)(ws + WS_B1T);
  float* w2t  = (float*)(ws + WS_W2T);
  float* u_ws = (float*)(ws + WS_U);
  float* dh_ws= (float*)(ws + WS_DH);

  k_zero<<<dim3(64), dim3(256), 0, stream>>>((uint4*)ws, (int)(WS_ZEND/16u));
  k_prep<<<dim3(720), dim3(256), 0, stream>>>(ln_g, ln_b, W_u, b_u, dln_g, dln_b, W_db, b_db,
                                              adj, W1, b1, W2, Wc, cst, w1t0, w1t1, b1t, w2t,
                                              out + O_A);
  k_lngemm<<<dim3(256), dim3(512), 0, stream>>>(feat, Wc, cst, u_ws, dh_ws);
  k_causal<<<dim3(1024), dim3(256), 0, stream>>>(u_ws, out + O_A, w1t0, w1t1, b1t, w2t, b2,
                                                 out + O_ZC);
  k_domain<<<dim3(256), dim3(256), 0, stream>>>(dh_ws, W_mu, b_mu, W_lv, b_lv, eps, out, wsd);
  k_rownorm<<<dim3(1024), dim3(256), 0, stream>>>(out, xnc, xnd);
  k_pass1<<<dim3(529), dim3(256), 0, stream>>>(out, xnc, xnd,
                                               (unsigned long long*)h1c,
                                               (unsigned long long*)h1d, out);
  k_pass2<<<dim3(528), dim3(256), 0, stream>>>(out, xnc, xnd, h1c, h1d,
                                               (unsigned long long*)m2c,
                                               (unsigned long long*)m2d);
  k_scan2<<<dim3(2), dim3(256), 0, stream>>>(h1c, h1d, m2c, m2d, wsf);
  k_hsic<<<dim3(528), dim3(256), 0, stream>>>(out, xnc, xnd, wsf, wsd, rsc, rsd);
  k_combine<<<dim3(1), dim3(256), 0, stream>>>(wsd, rsc, rsd, out);
}

// Round 7
// 444.549 us; speedup vs baseline: 1.9628x; 1.3223x over previous
//
#include <hip/hip_runtime.h>
#include <math.h>

// ---------------- problem constants ----------------
#define NB 4096
#define ND 1024

// d_out float offsets
#define O_ZC   0
#define O_ZD   262144
#define O_MU   327680
#define O_LV   393216
#define O_A    458752
#define O_DAG  462848
#define O_HSIC 462849
#define O_KL   462850

// ws byte offsets (zeroed region: [0, WS_ZEND))
#define WS_H1C    256u
#define WS_H1D    1280u
#define WS_M2C    2304u
#define WS_M2D    35072u
#define WS_RSC    67840u
#define WS_RSD    84224u
#define WS_ZEND   100608u
// non-zeroed scratch
#define WS_XNC    100608u
#define WS_XND    116992u
#define WS_WC     133376u
#define WS_CST    657664u
#define WS_W1T0   658176u
#define WS_W1T1   674560u
#define WS_B1T    690944u
#define WS_W2T    707328u
#define WS_U      723712u
#define WS_DH     1772288u

// fast erf-based gelu: A&S 7.1.26, |err| <= 1.5e-7, branch-free
__device__ __forceinline__ float gelu_f(float x){
  float y = fabsf(x) * 0.70710678118654752440f;
  float t = 1.0f / (1.0f + 0.3275911f * y);
  float poly = t*(0.254829592f + t*(-0.284496736f + t*(1.421413741f + t*(-1.453152027f + t*1.061405429f))));
  float e = __expf(-y*y);
  float er = 1.0f - poly*e;
  float s = copysignf(er, x);
  return 0.5f * x * (1.0f + s);
}

// triangle block map: b -> (bi <= bj), b = bj*(bj+1)/2 + bi
__device__ __forceinline__ void tri_map(int b, int& bi, int& bj){
  int r = (int)((sqrtf(8.0f*(float)b + 1.0f) - 1.0f) * 0.5f);
  while ((r+1)*(r+2)/2 <= b) r++;
  while (r*(r+1)/2 > b) r--;
  bj = r; bi = b - r*(r+1)/2;
}

// packed (u64) staggered histogram flush: hist has 2*n2 u32 bins, g is u64[n2]
__device__ __forceinline__ void flush_hist(const unsigned* __restrict__ hist,
                                           unsigned long long* __restrict__ g,
                                           int n2, int t, int salt){
  for (int e = t; e < n2; e += 256){
    int idx = (e + salt) & (n2 - 1);
    unsigned lo = hist[2*idx], hi = hist[2*idx + 1];
    if (lo | hi)
      atomicAdd(&g[idx], (unsigned long long)lo | ((unsigned long long)hi << 32));
  }
}

// ---------------- zero scratch ----------------
__global__ __launch_bounds__(256) void k_zero(uint4* p, int n){
  uint4 z; z.x = 0; z.y = 0; z.z = 0; z.w = 0;
  for (int i = blockIdx.x*256 + threadIdx.x; i < n; i += gridDim.x*256) p[i] = z;
}

// ---------------- prep: folded weights, A, consts, causal transposes ----------------
__global__ __launch_bounds__(256) void k_prep(
    const float* __restrict__ ln_g, const float* __restrict__ ln_b,
    const float* __restrict__ W_u,  const float* __restrict__ b_u,
    const float* __restrict__ dln_g,const float* __restrict__ dln_b,
    const float* __restrict__ W_db, const float* __restrict__ b_db,
    const float* __restrict__ adj,  const float* __restrict__ W1,
    const float* __restrict__ b1,   const float* __restrict__ W2,
    float* __restrict__ Wc, float* __restrict__ cst,
    float* __restrict__ w1t0, float* __restrict__ w1t1,
    float* __restrict__ b1t,  float* __restrict__ w2t,
    float* __restrict__ outA){
  __shared__ float red[256];
  int t = threadIdx.x, b = blockIdx.x;
  if (b < 512){
    int e = b*256 + t; int c = e & 127, d = e >> 7;
    Wc[e] = (c < 64) ? ln_g[d]*W_u[d*64 + c] : dln_g[d]*W_db[d*64 + (c-64)];
  } else if (b < 528){
    int e = (b-512)*256 + t; int i = e >> 6, j = e & 63;
    float a = 1.0f/(1.0f + __expf(-adj[e]));
    outA[e] = (i == j) ? 0.0f : a;
  } else if (b < 656){
    int col = b - 528;
    float p = 0.0f;
    for (int d = t; d < 1024; d += 256)
      p += (col < 64) ? ln_b[d]*W_u[d*64 + col] : dln_b[d]*W_db[d*64 + (col-64)];
    red[t] = p; __syncthreads();
    for (int off = 128; off > 0; off >>= 1){ if (t < off) red[t] += red[t+off]; __syncthreads(); }
    if (t == 0) cst[col] = red[0] + ((col < 64) ? b_u[col] : b_db[col-64]);
  } else {
    int e = (b-656)*256 + t; int which = e >> 12, r = e & 4095;
    int j = r >> 6, k = r & 63;
    if (which == 0)      w1t0[j*64+k] = W1[k*128 + j];
    else if (which == 1) w1t1[j*64+k] = W1[k*128 + 64 + j];
    else if (which == 2) b1t [j*64+k] = b1[k*64 + j];
    else                 w2t [j*64+k] = W2[k*64 + j];
  }
}

// ---------------- LN + dual GEMM (u pre-bias, dh pre-gelu) ----------------
__global__ __launch_bounds__(512) void k_lngemm(const float* __restrict__ feat,
    const float* __restrict__ Wc, const float* __restrict__ cst,
    float* __restrict__ u_ws, float* __restrict__ dh_ws){
  __shared__ float xh[16][1024];   // 64KB
  int t = threadIdx.x, b = blockIdx.x;
  {
    int row = t >> 5, lane = t & 31;
    const float4* src = (const float4*)(feat + (b*16 + row)*1024);
    float4 v[8]; float s = 0.0f, s2 = 0.0f;
    #pragma unroll
    for (int q = 0; q < 8; q++){
      v[q] = src[lane + q*32];
      s += v[q].x + v[q].y + v[q].z + v[q].w;
      s2 = fmaf(v[q].x,v[q].x, fmaf(v[q].y,v[q].y, fmaf(v[q].z,v[q].z, fmaf(v[q].w,v[q].w, s2))));
    }
    #pragma unroll
    for (int off = 1; off < 32; off <<= 1){ s += __shfl_xor(s, off); s2 += __shfl_xor(s2, off); }
    float mean = s * (1.0f/1024.0f);
    float var  = s2 * (1.0f/1024.0f) - mean*mean;
    float rs = rsqrtf(var + 1e-5f);
    float4* dst = (float4*)&xh[row][0];
    #pragma unroll
    for (int q = 0; q < 8; q++){
      float4 w; w.x = (v[q].x-mean)*rs; w.y = (v[q].y-mean)*rs;
      w.z = (v[q].z-mean)*rs; w.w = (v[q].w-mean)*rs;
      dst[lane + q*32] = w;
    }
  }
  __syncthreads();
  int col = t & 127, rg = t >> 7;    // rg in [0,4): 4 rows each
  float acc[4] = {0,0,0,0};
  for (int d0 = 0; d0 < 1024; d0 += 4){
    float w0 = Wc[(d0  )*128 + col];
    float w1 = Wc[(d0+1)*128 + col];
    float w2 = Wc[(d0+2)*128 + col];
    float w3 = Wc[(d0+3)*128 + col];
    #pragma unroll
    for (int r = 0; r < 4; r++){
      float4 x = *(const float4*)&xh[rg*4 + r][d0];
      acc[r] = fmaf(x.x,w0, fmaf(x.y,w1, fmaf(x.z,w2, fmaf(x.w,w3, acc[r]))));
    }
  }
  float cc = cst[col];
  #pragma unroll
  for (int r = 0; r < 4; r++){
    int grow = b*16 + rg*4 + r;
    float o = acc[r] + cc;
    if (col < 64) u_ws[grow*64 + col] = o;
    else          dh_ws[grow*64 + (col-64)] = o;
  }
}

// ---------------- causal structural loop (wave per row) + zc row-norm ----------------
__global__ __launch_bounds__(256) void k_causal(const float* __restrict__ u_ws,
    const float* __restrict__ A_g, const float* __restrict__ w1t0g, const float* __restrict__ w1t1g,
    const float* __restrict__ b1tg, const float* __restrict__ w2tg, const float* __restrict__ b2_g,
    float* __restrict__ zc_out, float* __restrict__ xnc){
  __shared__ float w1t0[4096], w1t1[4096];
  __shared__ float zbuf[4][64];
  int t = threadIdx.x;
  for (int e = t; e < 4096; e += 256){ w1t0[e] = w1t0g[e]; w1t1[e] = w1t1g[e]; }
  int w = t >> 6, k = t & 63;
  int row = blockIdx.x*4 + w;
  float uu = u_ws[row*64 + k];
  float b2v = b2_g[k];
  float z = uu;
  __syncthreads();
  #pragma unroll
  for (int itr = 0; itr < 2; ++itr){
    zbuf[w][k] = z;
    float p0=0.f,p1=0.f,p2=0.f,p3=0.f;
    #pragma unroll
    for (int j0 = 0; j0 < 64; j0 += 4){
      float4 zz = *(const float4*)&zbuf[w][j0];
      p0 = fmaf(zz.x, A_g[(j0+0)*64 + k], p0);
      p1 = fmaf(zz.y, A_g[(j0+1)*64 + k], p1);
      p2 = fmaf(zz.z, A_g[(j0+2)*64 + k], p2);
      p3 = fmaf(zz.w, A_g[(j0+3)*64 + k], p3);
    }
    float p = (p0+p1)+(p2+p3);
    float a0=0.f, a1=0.f;
    #pragma unroll 8
    for (int j = 0; j < 64; j += 2){
      float pre0 = fmaf(p, w1t0[j*64+k],     fmaf(uu, w1t1[j*64+k],     b1tg[j*64+k]));
      float pre1 = fmaf(p, w1t0[(j+1)*64+k], fmaf(uu, w1t1[(j+1)*64+k], b1tg[(j+1)*64+k]));
      a0 = fmaf(gelu_f(pre0), w2tg[j*64+k],     a0);
      a1 = fmaf(gelu_f(pre1), w2tg[(j+1)*64+k], a1);
    }
    z = a0 + a1 + b2v;
  }
  zc_out[row*64 + k] = z;
  float sq = z*z;
  #pragma unroll
  for (int off = 1; off < 64; off <<= 1) sq += __shfl_xor(sq, off);
  if (k == 0) xnc[row] = sq;
}

// ---------------- domain head: gelu, mu/lv, z_d, KL + zd row-norm ----------------
__global__ __launch_bounds__(256) void k_domain(const float* __restrict__ dh_ws,
    const float* __restrict__ Wmu, const float* __restrict__ bmu,
    const float* __restrict__ Wlv, const float* __restrict__ blv,
    const float* __restrict__ eps, float* __restrict__ out, double* __restrict__ wsd,
    float* __restrict__ xnd){
  __shared__ float hb[4][64];
  int t = threadIdx.x, w = t >> 6, l = t & 63;
  int dd = l & 15;
  double klacc = 0.0;
  for (int it = 0; it < 4; ++it){
    int row = blockIdx.x*16 + it*4 + w;
    hb[w][l] = gelu_f(dh_ws[row*64 + l]);
    float val = 0.0f;
    if (l < 32){
      const float* W = (l < 16) ? Wmu : Wlv;
      float a = (l < 16) ? bmu[dd] : blv[dd];
      for (int j = 0; j < 64; j++) a = fmaf(hb[w][j], W[j*16 + dd], a);
      val = a;
    }
    float mu = __shfl(val, dd);
    float lv = __shfl(val, 16 + dd);
    float kle = 0.0f, zs = 0.0f;
    if (l < 16){
      out[O_MU + row*16 + dd] = mu;
      out[O_LV + row*16 + dd] = lv;
      float zdv = fmaf(eps[row*16 + dd], __expf(0.5f*lv), mu);
      out[O_ZD + row*16 + dd] = zdv;
      zs = zdv*zdv;
      kle = 1.0f + lv - mu*mu - __expf(lv);
    }
    #pragma unroll
    for (int off = 1; off < 16; off <<= 1){ kle += __shfl_xor(kle, off); zs += __shfl_xor(zs, off); }
    if (l == 0){ klacc += (double)kle; xnd[row] = zs; }
  }
  if (l == 0) atomicAdd(&wsd[1], klacc);
}

// ---------------- tile staging + 8x8 dot micro-kernel ----------------
template<int DIM>
__device__ __forceinline__ void stageT(const float* __restrict__ src, float* __restrict__ dst,
                                       int i0, int t){
  for (int e = t; e < DIM*128; e += 256){
    int k = e & (DIM-1);
    int r = e >> (DIM == 64 ? 6 : 4);
    dst[k*128 + (r ^ ((k & 7) << 2))] = src[(i0 + r)*DIM + k];
  }
}

template<int KDIM>
__device__ __forceinline__ void dot8x8(const float* __restrict__ LA, const float* __restrict__ LB,
                                       int tx8, int ty8, float acc[8][8]){
  #pragma unroll 8
  for (int k = 0; k < KDIM; k++){
    int s = (k & 7) << 2;
    const float* pa = LA + k*128;
    const float* pb = LB + k*128;
    float4 a0 = *(const float4*)(pa + ((ty8    ) ^ s));
    float4 a1 = *(const float4*)(pa + ((ty8 + 4) ^ s));
    float4 b0 = *(const float4*)(pb + ((tx8    ) ^ s));
    float4 b1 = *(const float4*)(pb + ((tx8 + 4) ^ s));
    float av[8] = {a0.x,a0.y,a0.z,a0.w,a1.x,a1.y,a1.z,a1.w};
    float bv[8] = {b0.x,b0.y,b0.z,b0.w,b1.x,b1.y,b1.z,b1.w};
    #pragma unroll
    for (int ii = 0; ii < 8; ii++)
      #pragma unroll
      for (int jj = 0; jj < 8; jj++)
        acc[ii][jj] = fmaf(av[ii], bv[jj], acc[ii][jj]);
  }
}

// ---------------- dag: expm via scaling & squaring (single block) ----------------
__device__ void dag_mm(float* __restrict__ C, const float* __restrict__ Am, const float* __restrict__ Bm,
                       const float* __restrict__ Xm, float cI, float cX, int t, bool addG){
  int tx = t & 15, ty = t >> 4;
  float acc[4][4] = {};
  for (int k0 = 0; k0 < 64; k0 += 4){
    float4 a0 = *(const float4*)&Am[(ty*4+0)*64 + k0];
    float4 a1 = *(const float4*)&Am[(ty*4+1)*64 + k0];
    float4 a2 = *(const float4*)&Am[(ty*4+2)*64 + k0];
    float4 a3 = *(const float4*)&Am[(ty*4+3)*64 + k0];
    float4 b0 = *(const float4*)&Bm[(k0+0)*64 + tx*4];
    float4 b1 = *(const float4*)&Bm[(k0+1)*64 + tx*4];
    float4 b2 = *(const float4*)&Bm[(k0+2)*64 + tx*4];
    float4 b3 = *(const float4*)&Bm[(k0+3)*64 + tx*4];
#define MQ(ii, AV) \
    acc[ii][0] = fmaf(AV.x,b0.x, fmaf(AV.y,b1.x, fmaf(AV.z,b2.x, fmaf(AV.w,b3.x, acc[ii][0])))); \
    acc[ii][1] = fmaf(AV.x,b0.y, fmaf(AV.y,b1.y, fmaf(AV.z,b2.y, fmaf(AV.w,b3.y, acc[ii][1])))); \
    acc[ii][2] = fmaf(AV.x,b0.z, fmaf(AV.y,b1.z, fmaf(AV.z,b2.z, fmaf(AV.w,b3.z, acc[ii][2])))); \
    acc[ii][3] = fmaf(AV.x,b0.w, fmaf(AV.y,b1.w, fmaf(AV.z,b2.w, fmaf(AV.w,b3.w, acc[ii][3]))));
    MQ(0,a0) MQ(1,a1) MQ(2,a2) MQ(3,a3)
#undef MQ
  }
  #pragma unroll
  for (int ii = 0; ii < 4; ii++)
    #pragma unroll
    for (int jj = 0; jj < 4; jj++){
      int i = ty*4 + ii, j = tx*4 + jj;
      float v = acc[ii][jj];
      if (addG) v += ((i == j) ? cI : 0.0f) + cX * Xm[i*64 + j];
      C[i*64 + j] = v;
    }
  __syncthreads();
}

__device__ void dag_expm(float* ldsA, float* ldsB, const float* __restrict__ A_g,
                         float* __restrict__ dout){
  int t = threadIdx.x;
  float* X  = ldsA;
  float* X2 = ldsA + 4096;
  float* P  = ldsB;
  float* Pn = ldsB + 4096;
  for (int e = t; e < 4096; e += 256){ float a = A_g[e]; X[e] = a*a; }
  __syncthreads();
  int l = t & 63;
  float cs = 0.0f;
  for (int i = 0; i < 64; i++) cs += X[i*64 + l];
  #pragma unroll
  for (int off = 1; off < 64; off <<= 1) cs = fmaxf(cs, __shfl_xor(cs, off));
  int s_ = 0;
  if (cs > 2.0f) s_ = (int)ceilf(log2f(cs * 0.5f));
  if (s_ < 0) s_ = 0; if (s_ > 12) s_ = 12;
  float sc = exp2f((float)(-s_));
  __syncthreads();
  for (int e = t; e < 4096; e += 256) X[e] *= sc;
  __syncthreads();
  dag_mm(X2, X, X, X, 0.0f, 0.0f, t, false);
  const float C12 = 2.0876756987868099e-9f, C13 = 1.6059043836821613e-10f;
  for (int e = t; e < 4096; e += 256){
    int i = e >> 6, j = e & 63;
    P[e] = C13*X[e] + ((i == j) ? C12 : 0.0f);
  }
  __syncthreads();
  const float cf[12] = {1.0f, 1.0f, 0.5f, 1.0f/6.0f, 1.0f/24.0f, 1.0f/120.0f,
                        1.0f/720.0f, 1.0f/5040.0f, 1.0f/40320.0f, 1.0f/362880.0f,
                        1.0f/3628800.0f, 1.0f/39916800.0f};
  #pragma unroll
  for (int g = 5; g >= 0; --g){
    dag_mm(Pn, X2, P, X, cf[2*g], cf[2*g+1], t, true);
    float* tmp = P; P = Pn; Pn = tmp;
  }
  for (int q = 0; q < s_; ++q){
    dag_mm(Pn, P, P, X, 0.0f, 0.0f, t, false);
    float* tmp = P; P = Pn; Pn = tmp;
  }
  if (t < 64){
    float tr = P[t*65];
    #pragma unroll
    for (int off = 1; off < 64; off <<= 1) tr += __shfl_xor(tr, off);
    if (t == 0) dout[O_DAG] = tr - 64.0f;
  }
}

// ---------------- median pass 1: exponent histogram (256 bins x 32 replicas) ----------------
__global__ __launch_bounds__(256,1) void k_pass1(const float* __restrict__ out,
    const float* __restrict__ xnc, const float* __restrict__ xnd,
    unsigned* __restrict__ h1c, unsigned* __restrict__ h1d,
    float* __restrict__ dout){
  __shared__ __align__(16) float ldsA[8192];
  __shared__ __align__(16) float ldsB[8192];
  int t = threadIdx.x;
  if (blockIdx.x == 528){ dag_expm(ldsA, ldsB, out + O_A, dout); return; }
  int bi, bj; tri_map(blockIdx.x, bi, bj);
  bool diag = (bi == bj);
  int i0 = bi*128, j0 = bj*128;
  int tx = t & 15, ty = t >> 4, tx8 = tx*8, ty8 = ty*8;
  int rep = t & 31;
  unsigned* hist = (unsigned*)ldsA;     // 256 bins x 32 reps = 8192 u32, reused after dots
  stageT<64>(out + O_ZC, ldsA, i0, t);
  stageT<64>(out + O_ZC, ldsB, j0, t);
  float xi[8], xj[8];
  #pragma unroll
  for (int ii = 0; ii < 8; ii++){ xi[ii] = xnc[i0+ty8+ii]; xj[ii] = xnc[j0+tx8+ii]; }
  __syncthreads();
  float acc[8][8] = {};
  dot8x8<64>(ldsA, ldsB, tx8, ty8, acc);
  __syncthreads();
  for (int e = t; e < 8192; e += 256) hist[e] = 0u;
  __syncthreads();
  #pragma unroll
  for (int ii = 0; ii < 8; ii++)
    #pragma unroll
    for (int jj = 0; jj < 8; jj++){
      float d2 = xi[ii] + xj[jj] - 2.0f*acc[ii][jj];
      bool take = diag ? ((i0+ty8+ii) < (j0+tx8+jj)) : true;
      if (take && d2 > 0.0f)
        atomicAdd(&hist[((__float_as_uint(d2) >> 23) << 5) | rep], 1u);
    }
  __syncthreads();
  {
    int b = (t + blockIdx.x*37) & 255;
    unsigned s = 0;
    #pragma unroll
    for (int rr = 0; rr < 32; rr++) s += hist[(b << 5) | ((rr + t) & 31)];
    if (s) atomicAdd(&h1c[b], s);
  }
  __syncthreads();
  // d phase
  stageT<16>(out + O_ZD, ldsB, i0, t);
  stageT<16>(out + O_ZD, ldsB + 2048, j0, t);
  #pragma unroll
  for (int ii = 0; ii < 8; ii++){ xi[ii] = xnd[i0+ty8+ii]; xj[ii] = xnd[j0+tx8+ii]; }
  __syncthreads();
  float acd[8][8] = {};
  dot8x8<16>(ldsB, ldsB + 2048, tx8, ty8, acd);
  __syncthreads();
  for (int e = t; e < 8192; e += 256) hist[e] = 0u;
  __syncthreads();
  #pragma unroll
  for (int ii = 0; ii < 8; ii++)
    #pragma unroll
    for (int jj = 0; jj < 8; jj++){
      float d2 = xi[ii] + xj[jj] - 2.0f*acd[ii][jj];
      bool take = diag ? ((i0+ty8+ii) < (j0+tx8+jj)) : true;
      if (take && d2 > 0.0f)
        atomicAdd(&hist[((__float_as_uint(d2) >> 23) << 5) | rep], 1u);
    }
  __syncthreads();
  {
    int b = (t + blockIdx.x*53) & 255;
    unsigned s = 0;
    #pragma unroll
    for (int rr = 0; rr < 32; rr++) s += hist[(b << 5) | ((rr + t) & 31)];
    if (s) atomicAdd(&h1d[b], s);
  }
}

// find target exponent bin + rank within it from 256-bin histogram
__device__ unsigned find_bin256(const unsigned* __restrict__ h1, unsigned* sbuf, int t,
                                unsigned* k2out){
  unsigned part = h1[t];
  sbuf[t] = part;
  __syncthreads();
  for (int off = 1; off < 256; off <<= 1){
    unsigned v = (t >= off) ? sbuf[t-off] : 0u;
    __syncthreads();
    sbuf[t] += v;
    __syncthreads();
  }
  unsigned total = sbuf[255];
  unsigned pre = sbuf[t] - part;
  __syncthreads();
  if (t == 0){ sbuf[0] = 0xFFFFFFFFu; sbuf[1] = 0u; }
  __syncthreads();
  if (total > 0){
    unsigned rt = (total - 1u) >> 1;   // lower median rank
    if (rt >= pre && rt < pre + part){ sbuf[0] = (unsigned)t; sbuf[1] = rt - pre; }
  }
  __syncthreads();
  unsigned b1 = sbuf[0];
  unsigned k2 = sbuf[1];
  __syncthreads();
  if (k2out) *k2out = k2;
  return b1;
}

// ---------------- median pass 2: 13 mantissa bits (8192 bins) within selected exponent ----------------
__global__ __launch_bounds__(256,1) void k_pass2(const float* __restrict__ out,
    const float* __restrict__ xnc, const float* __restrict__ xnd,
    const unsigned* __restrict__ h1c, const unsigned* __restrict__ h1d,
    unsigned long long* __restrict__ m2c, unsigned long long* __restrict__ m2d){
  __shared__ __align__(16) float ldsA[8192];
  __shared__ __align__(16) float ldsB[8192];
  unsigned* hist = (unsigned*)ldsA;            // 8192 bins, reused after dots
  int t = threadIdx.x;
  unsigned b1c = find_bin256(h1c, (unsigned*)ldsA, t, nullptr);
  unsigned b1d = find_bin256(h1d, (unsigned*)ldsA, t, nullptr);
  int bi, bj; tri_map(blockIdx.x, bi, bj);
  bool diag = (bi == bj);
  int i0 = bi*128, j0 = bj*128;
  int tx = t & 15, ty = t >> 4, tx8 = tx*8, ty8 = ty*8;
  // ---- c phase ----
  stageT<64>(out + O_ZC, ldsA, i0, t);
  stageT<64>(out + O_ZC, ldsB, j0, t);
  float xi[8], xj[8];
  #pragma unroll
  for (int ii = 0; ii < 8; ii++){ xi[ii] = xnc[i0+ty8+ii]; xj[ii] = xnc[j0+tx8+ii]; }
  __syncthreads();
  float acc[8][8] = {};
  dot8x8<64>(ldsA, ldsB, tx8, ty8, acc);
  __syncthreads();
  for (int e = t; e < 8192; e += 256) hist[e] = 0u;
  __syncthreads();
  #pragma unroll
  for (int ii = 0; ii < 8; ii++)
    #pragma unroll
    for (int jj = 0; jj < 8; jj++){
      float d2 = xi[ii] + xj[jj] - 2.0f*acc[ii][jj];
      unsigned u = __float_as_uint(d2);
      bool take = (diag ? ((i0+ty8+ii) < (j0+tx8+jj)) : true) && d2 > 0.0f && (u >> 23) == b1c;
      if (take) atomicAdd(&hist[(u >> 10) & 0x1FFFu], 1u);
    }
  __syncthreads();
  flush_hist(hist, m2c, 4096, t, blockIdx.x * 37);
  __syncthreads();
  // ---- d phase ----
  stageT<16>(out + O_ZD, ldsB, i0, t);
  stageT<16>(out + O_ZD, ldsB + 2048, j0, t);
  #pragma unroll
  for (int ii = 0; ii < 8; ii++){ xi[ii] = xnd[i0+ty8+ii]; xj[ii] = xnd[j0+tx8+ii]; }
  __syncthreads();
  float acd[8][8] = {};
  dot8x8<16>(ldsB, ldsB + 2048, tx8, ty8, acd);
  __syncthreads();
  for (int e = t; e < 8192; e += 256) hist[e] = 0u;
  __syncthreads();
  #pragma unroll
  for (int ii = 0; ii < 8; ii++)
    #pragma unroll
    for (int jj = 0; jj < 8; jj++){
      float d2 = xi[ii] + xj[jj] - 2.0f*acd[ii][jj];
      unsigned u = __float_as_uint(d2);
      bool take = (diag ? ((i0+ty8+ii) < (j0+tx8+jj)) : true) && d2 > 0.0f && (u >> 23) == b1d;
      if (take) atomicAdd(&hist[(u >> 10) & 0x1FFFu], 1u);
    }
  __syncthreads();
  flush_hist(hist, m2d, 4096, t, blockIdx.x * 53);
}

// ---------------- median finalize: exponent + 13 mantissa bits -> midpoint -> gamma ----------------
__global__ __launch_bounds__(256) void k_scan2(const unsigned* __restrict__ h1c,
    const unsigned* __restrict__ h1d, const unsigned* __restrict__ m2c,
    const unsigned* __restrict__ m2d, float* __restrict__ wsf){
  __shared__ unsigned sbuf[256];
  __shared__ unsigned res[2];
  int t = threadIdx.x;
  bool isd = blockIdx.x != 0;
  const unsigned* h1 = isd ? h1d : h1c;
  const unsigned* m2 = isd ? m2d : m2c;
  unsigned k2;
  unsigned b1 = find_bin256(h1, sbuf, t, &k2);
  if (b1 == 0xFFFFFFFFu){
    if (t == 0) wsf[8 + blockIdx.x] = 0.5f;   // cnt==0 -> sigma=1
    return;
  }
  // scan m2 (8192 bins, 32 per thread)
  unsigned part = 0;
  #pragma unroll
  for (int i = 0; i < 32; i++) part += m2[t*32 + i];
  sbuf[t] = part; __syncthreads();
  for (int off = 1; off < 256; off <<= 1){
    unsigned v = (t >= off) ? sbuf[t-off] : 0u; __syncthreads(); sbuf[t] += v; __syncthreads();
  }
  unsigned pre = sbuf[t] - part;
  __syncthreads();
  if (t == 0) res[0] = 0u;
  __syncthreads();
  if (k2 >= pre && k2 < pre + part){
    unsigned run = pre;
    #pragma unroll
    for (int i = 0; i < 32; i++){
      unsigned c = m2[t*32 + i];
      if (k2 < run + c){ res[0] = (unsigned)(t*32 + i); break; }
      run += c;
    }
  }
  __syncthreads();
  if (t == 0){
    unsigned med_bits = (b1 << 23) | (res[0] << 10) | 512u;   // midpoint, rel err ~6e-5
    float med = __uint_as_float(med_bits);
    float sig = fmaxf(sqrtf(med), 1e-6f);
    wsf[8 + blockIdx.x] = 1.0f/(2.0f*sig*sig);
  }
}

// ---------------- HSIC accumulation pass (triangle) ----------------
__global__ __launch_bounds__(256,1) void k_hsic(const float* __restrict__ out,
    const float* __restrict__ xnc, const float* __restrict__ xnd,
    const float* __restrict__ wsf, double* __restrict__ wsd,
    float* __restrict__ rsc, float* __restrict__ rsd){
  __shared__ __align__(16) float ldsA[8192];
  __shared__ __align__(16) float ldsB[8192];
  int t = threadIdx.x;
  int bi, bj; tri_map(blockIdx.x, bi, bj);
  bool diag = (bi == bj);
  int i0 = bi*128, j0 = bj*128;
  int tx = t & 15, ty = t >> 4, tx8 = tx*8, ty8 = ty*8;
  float gc = wsf[8], gd = wsf[9];
  stageT<64>(out + O_ZC, ldsA, i0, t);
  stageT<64>(out + O_ZC, ldsB, j0, t);
  float xi[8], xj[8];
  #pragma unroll
  for (int ii = 0; ii < 8; ii++){ xi[ii] = xnc[i0+ty8+ii]; xj[ii] = xnc[j0+tx8+ii]; }
  __syncthreads();
  float kc[8][8] = {};
  dot8x8<64>(ldsA, ldsB, tx8, ty8, kc);
  #pragma unroll
  for (int ii = 0; ii < 8; ii++)
    #pragma unroll
    for (int jj = 0; jj < 8; jj++)
      kc[ii][jj] = __expf(-gc * fmaxf(xi[ii] + xj[jj] - 2.0f*kc[ii][jj], 0.0f));
  __syncthreads();
  stageT<16>(out + O_ZD, ldsA, i0, t);
  stageT<16>(out + O_ZD, ldsA + 2048, j0, t);
  #pragma unroll
  for (int ii = 0; ii < 8; ii++){ xi[ii] = xnd[i0+ty8+ii]; xj[ii] = xnd[j0+tx8+ii]; }
  __syncthreads();
  float ad[8][8] = {};
  dot8x8<16>(ldsA, ldsA + 2048, tx8, ty8, ad);
  float t1p = 0.0f;
  float rc[8] = {}, rd[8] = {}, cc[8] = {}, cd[8] = {};
  #pragma unroll
  for (int ii = 0; ii < 8; ii++)
    #pragma unroll
    for (int jj = 0; jj < 8; jj++){
      float kd = __expf(-gd * fmaxf(xi[ii] + xj[jj] - 2.0f*ad[ii][jj], 0.0f));
      float c = kc[ii][jj];
      t1p = fmaf(c, kd, t1p);
      rc[ii] += c; rd[ii] += kd;
      cc[jj] += c; cd[jj] += kd;
    }
  __syncthreads();
  float* red = ldsB;           // [0,128)rowC [128,256)rowD [256,384)colC [384,512)colD [512,516)t1
  red[t] = 0.0f; red[t + 256] = 0.0f;
  __syncthreads();
  #pragma unroll
  for (int ii = 0; ii < 8; ii++){
    atomicAdd(&red[ty8 + ii], rc[ii]);
    atomicAdd(&red[128 + ty8 + ii], rd[ii]);
  }
  if (!diag){
    #pragma unroll
    for (int jj = 0; jj < 8; jj++){
      atomicAdd(&red[256 + tx8 + jj], cc[jj]);
      atomicAdd(&red[384 + tx8 + jj], cd[jj]);
    }
  }
  #pragma unroll
  for (int off = 1; off < 64; off <<= 1) t1p += __shfl_xor(t1p, off);
  if ((t & 63) == 0) red[512 + (t >> 6)] = t1p;
  __syncthreads();
  if (t < 128){ atomicAdd(&rsc[i0 + t], red[t]); atomicAdd(&rsd[i0 + t], red[128 + t]); }
  else if (!diag){ atomicAdd(&rsc[j0 + t - 128], red[256 + t - 128]); atomicAdd(&rsd[j0 + t - 128], red[384 + t - 128]); }
  if (t == 0){
    double s = (double)red[512] + (double)red[513] + (double)red[514] + (double)red[515];
    if (!diag) s *= 2.0;
    atomicAdd(&wsd[0], s);
  }
}

// ---------------- final combine ----------------
__global__ __launch_bounds__(256) void k_combine(const double* __restrict__ wsd,
    const float* __restrict__ rsc, const float* __restrict__ rsd, float* __restrict__ dout){
  __shared__ double r1[256], r2[256], r3[256];
  int t = threadIdx.x;
  double sc = 0.0, sd = 0.0, pp = 0.0;
  for (int i = t; i < 4096; i += 256){
    double a = rsc[i], b = rsd[i];
    sc += a; sd += b; pp += a*b;
  }
  r1[t] = sc; r2[t] = sd; r3[t] = pp; __syncthreads();
  for (int off = 128; off > 0; off >>= 1){
    if (t < off){ r1[t] += r1[t+off]; r2[t] += r2[t+off]; r3[t] += r3[t+off]; }
    __syncthreads();
  }
  if (t == 0){
    double n = 4096.0;
    double T1 = wsd[0];
    double hs = (T1 - 2.0*r3[0]/n + r1[0]*r2[0]/(n*n)) / ((n-1.0)*(n-1.0));
    dout[O_HSIC] = (float)hs;
    dout[O_KL]   = (float)(-0.5 * wsd[1] / n);
  }
}

// ---------------- launcher ----------------
extern "C" void kernel_launch(void* const* d_in, const int* in_sizes, int n_in,
                              void* d_out, int out_size, void* d_ws, size_t ws_size,
                              hipStream_t stream){
  (void)in_sizes; (void)n_in; (void)out_size; (void)ws_size;
  const float* feat  = (const float*)d_in[0];
  const float* ln_g  = (const float*)d_in[1];
  const float* ln_b  = (const float*)d_in[2];
  const float* W_u   = (const float*)d_in[3];
  const float* b_u   = (const float*)d_in[4];
  const float* W1    = (const float*)d_in[5];
  const float* b1    = (const float*)d_in[6];
  const float* W2    = (const float*)d_in[7];
  const float* b2    = (const float*)d_in[8];
  const float* adj   = (const float*)d_in[9];
  const float* dln_g = (const float*)d_in[10];
  const float* dln_b = (const float*)d_in[11];
  const float* W_db  = (const float*)d_in[12];
  const float* b_db  = (const float*)d_in[13];
  const float* W_mu  = (const float*)d_in[14];
  const float* b_mu  = (const float*)d_in[15];
  const float* W_lv  = (const float*)d_in[16];
  const float* b_lv  = (const float*)d_in[17];
  const float* eps   = (const float*)d_in[18];
  float* out = (float*)d_out;
  char* ws = (char*)d_ws;
  float*  wsf = (float*)ws;
  double* wsd = (double*)ws;
  unsigned* h1c  = (unsigned*)(ws + WS_H1C);
  unsigned* h1d  = (unsigned*)(ws + WS_H1D);
  unsigned* m2c  = (unsigned*)(ws + WS_M2C);
  unsigned* m2d  = (unsigned*)(ws + WS_M2D);
  float* rsc  = (float*)(ws + WS_RSC);
  float* rsd  = (float*)(ws + WS_RSD);
  float* xnc  = (float*)(ws + WS_XNC);
  float* xnd  = (float*)(ws + WS_XND);
  float* Wc   = (float*)(ws + WS_WC);
  float* cst  = (float*)(ws + WS_CST);
  float* w1t0 = (float*)(ws + WS_W1T0);
  float* w1t1 = (float*)(ws + WS_W1T1);
  float* b1t  = (float*)(ws + WS_B1T);
  float* w2t  = (float*)(ws + WS_W2T);
  float* u_ws = (float*)(ws + WS_U);
  float* dh_ws= (float*)(ws + WS_DH);

  k_zero<<<dim3(64), dim3(256), 0, stream>>>((uint4*)ws, (int)(WS_ZEND/16u));
  k_prep<<<dim3(720), dim3(256), 0, stream>>>(ln_g, ln_b, W_u, b_u, dln_g, dln_b, W_db, b_db,
                                              adj, W1, b1, W2, Wc, cst, w1t0, w1t1, b1t, w2t,
                                              out + O_A);
  k_lngemm<<<dim3(256), dim3(512), 0, stream>>>(feat, Wc, cst, u_ws, dh_ws);
  k_causal<<<dim3(1024), dim3(256), 0, stream>>>(u_ws, out + O_A, w1t0, w1t1, b1t, w2t, b2,
                                                 out + O_ZC, xnc);
  k_domain<<<dim3(256), dim3(256), 0, stream>>>(dh_ws, W_mu, b_mu, W_lv, b_lv, eps, out, wsd,
                                                xnd);
  k_pass1<<<dim3(529), dim3(256), 0, stream>>>(out, xnc, xnd, h1c, h1d, out);
  k_pass2<<<dim3(528), dim3(256), 0, stream>>>(out, xnc, xnd, h1c, h1d,
                                               (unsigned long long*)m2c,
                                               (unsigned long long*)m2d);
  k_scan2<<<dim3(2), dim3(256), 0, stream>>>(h1c, h1d, m2c, m2d, wsf);
  k_hsic<<<dim3(528), dim3(256), 0, stream>>>(out, xnc, xnd, wsf, wsd, rsc, rsd);
  k_combine<<<dim3(1), dim3(256), 0, stream>>>(wsd, rsc, rsd, out);
}

// Round 9
// 412.934 us; speedup vs baseline: 2.1131x; 1.0766x over previous
//
#include <hip/hip_runtime.h>
#include <math.h>

// ---------------- problem constants ----------------
#define NB 4096
#define ND 1024

// d_out float offsets
#define O_ZC   0
#define O_ZD   262144
#define O_MU   327680
#define O_LV   393216
#define O_A    458752
#define O_DAG  462848
#define O_HSIC 462849
#define O_KL   462850

// ws byte offsets (zeroed region: [0, WS_ZEND))
// h1c/h1d: 8 replicas x 256 u32; m2c/m2d: 8 replicas x 1024 u32 (as 512 u64)
#define WS_H1C    256u
#define WS_H1D    8448u
#define WS_M2C    16640u
#define WS_M2D    49408u
#define WS_RSC    82176u
#define WS_RSD    98560u
#define WS_ZEND   114944u
// non-zeroed scratch
#define WS_XNC    114944u
#define WS_XND    131328u
#define WS_WC     147712u
#define WS_CST    672000u
#define WS_W1T0   672512u
#define WS_W1T1   688896u
#define WS_B1T    705280u
#define WS_W2T    721664u
#define WS_U      738048u
#define WS_DH     1786624u

// fast erf-based gelu: A&S 7.1.26, |err| <= 1.5e-7, branch-free
__device__ __forceinline__ float gelu_f(float x){
  float y = fabsf(x) * 0.70710678118654752440f;
  float t = 1.0f / (1.0f + 0.3275911f * y);
  float poly = t*(0.254829592f + t*(-0.284496736f + t*(1.421413741f + t*(-1.453152027f + t*1.061405429f))));
  float e = __expf(-y*y);
  float er = 1.0f - poly*e;
  float s = copysignf(er, x);
  return 0.5f * x * (1.0f + s);
}

// triangle block map: b -> (bi <= bj), b = bj*(bj+1)/2 + bi
__device__ __forceinline__ void tri_map(int b, int& bi, int& bj){
  int r = (int)((sqrtf(8.0f*(float)b + 1.0f) - 1.0f) * 0.5f);
  while ((r+1)*(r+2)/2 <= b) r++;
  while (r*(r+1)/2 > b) r--;
  bj = r; bi = b - r*(r+1)/2;
}

// ---------------- zero scratch ----------------
__global__ __launch_bounds__(256) void k_zero(uint4* p, int n){
  uint4 z; z.x = 0; z.y = 0; z.z = 0; z.w = 0;
  for (int i = blockIdx.x*256 + threadIdx.x; i < n; i += gridDim.x*256) p[i] = z;
}

// ---------------- prep: folded weights, A, consts, causal transposes ----------------
__global__ __launch_bounds__(256) void k_prep(
    const float* __restrict__ ln_g, const float* __restrict__ ln_b,
    const float* __restrict__ W_u,  const float* __restrict__ b_u,
    const float* __restrict__ dln_g,const float* __restrict__ dln_b,
    const float* __restrict__ W_db, const float* __restrict__ b_db,
    const float* __restrict__ adj,  const float* __restrict__ W1,
    const float* __restrict__ b1,   const float* __restrict__ W2,
    float* __restrict__ Wc, float* __restrict__ cst,
    float* __restrict__ w1t0, float* __restrict__ w1t1,
    float* __restrict__ b1t,  float* __restrict__ w2t,
    float* __restrict__ outA){
  __shared__ float red[256];
  int t = threadIdx.x, b = blockIdx.x;
  if (b < 512){
    int e = b*256 + t; int c = e & 127, d = e >> 7;
    Wc[e] = (c < 64) ? ln_g[d]*W_u[d*64 + c] : dln_g[d]*W_db[d*64 + (c-64)];
  } else if (b < 528){
    int e = (b-512)*256 + t; int i = e >> 6, j = e & 63;
    float a = 1.0f/(1.0f + __expf(-adj[e]));
    outA[e] = (i == j) ? 0.0f : a;
  } else if (b < 656){
    int col = b - 528;
    float p = 0.0f;
    for (int d = t; d < 1024; d += 256)
      p += (col < 64) ? ln_b[d]*W_u[d*64 + col] : dln_b[d]*W_db[d*64 + (col-64)];
    red[t] = p; __syncthreads();
    for (int off = 128; off > 0; off >>= 1){ if (t < off) red[t] += red[t+off]; __syncthreads(); }
    if (t == 0) cst[col] = red[0] + ((col < 64) ? b_u[col] : b_db[col-64]);
  } else {
    int e = (b-656)*256 + t; int which = e >> 12, r = e & 4095;
    int j = r >> 6, k = r & 63;
    if (which == 0)      w1t0[j*64+k] = W1[k*128 + j];
    else if (which == 1) w1t1[j*64+k] = W1[k*128 + 64 + j];
    else if (which == 2) b1t [j*64+k] = b1[k*64 + j];
    else                 w2t [j*64+k] = W2[k*64 + j];
  }
}

// ---------------- LN + dual GEMM (u pre-bias, dh pre-gelu) ----------------
__global__ __launch_bounds__(512) void k_lngemm(const float* __restrict__ feat,
    const float* __restrict__ Wc, const float* __restrict__ cst,
    float* __restrict__ u_ws, float* __restrict__ dh_ws){
  __shared__ float xh[16][1024];   // 64KB
  int t = threadIdx.x, b = blockIdx.x;
  {
    int row = t >> 5, lane = t & 31;
    const float4* src = (const float4*)(feat + (b*16 + row)*1024);
    float4 v[8]; float s = 0.0f, s2 = 0.0f;
    #pragma unroll
    for (int q = 0; q < 8; q++){
      v[q] = src[lane + q*32];
      s += v[q].x + v[q].y + v[q].z + v[q].w;
      s2 = fmaf(v[q].x,v[q].x, fmaf(v[q].y,v[q].y, fmaf(v[q].z,v[q].z, fmaf(v[q].w,v[q].w, s2))));
    }
    #pragma unroll
    for (int off = 1; off < 32; off <<= 1){ s += __shfl_xor(s, off); s2 += __shfl_xor(s2, off); }
    float mean = s * (1.0f/1024.0f);
    float var  = s2 * (1.0f/1024.0f) - mean*mean;
    float rs = rsqrtf(var + 1e-5f);
    float4* dst = (float4*)&xh[row][0];
    #pragma unroll
    for (int q = 0; q < 8; q++){
      float4 w; w.x = (v[q].x-mean)*rs; w.y = (v[q].y-mean)*rs;
      w.z = (v[q].z-mean)*rs; w.w = (v[q].w-mean)*rs;
      dst[lane + q*32] = w;
    }
  }
  __syncthreads();
  int col = t & 127, rg = t >> 7;    // rg in [0,4): 4 rows each
  float acc[4] = {0,0,0,0};
  for (int d0 = 0; d0 < 1024; d0 += 4){
    float w0 = Wc[(d0  )*128 + col];
    float w1 = Wc[(d0+1)*128 + col];
    float w2 = Wc[(d0+2)*128 + col];
    float w3 = Wc[(d0+3)*128 + col];
    #pragma unroll
    for (int r = 0; r < 4; r++){
      float4 x = *(const float4*)&xh[rg*4 + r][d0];
      acc[r] = fmaf(x.x,w0, fmaf(x.y,w1, fmaf(x.z,w2, fmaf(x.w,w3, acc[r]))));
    }
  }
  float cc = cst[col];
  #pragma unroll
  for (int r = 0; r < 4; r++){
    int grow = b*16 + rg*4 + r;
    float o = acc[r] + cc;
    if (col < 64) u_ws[grow*64 + col] = o;
    else          dh_ws[grow*64 + (col-64)] = o;
  }
}

// ---------------- causal structural loop (wave per row) + zc row-norm ----------------
__global__ __launch_bounds__(256) void k_causal(const float* __restrict__ u_ws,
    const float* __restrict__ A_g, const float* __restrict__ w1t0g, const float* __restrict__ w1t1g,
    const float* __restrict__ b1tg, const float* __restrict__ w2tg, const float* __restrict__ b2_g,
    float* __restrict__ zc_out, float* __restrict__ xnc){
  __shared__ float w1t0[4096], w1t1[4096];
  __shared__ float zbuf[4][64];
  int t = threadIdx.x;
  for (int e = t; e < 4096; e += 256){ w1t0[e] = w1t0g[e]; w1t1[e] = w1t1g[e]; }
  int w = t >> 6, k = t & 63;
  int row = blockIdx.x*4 + w;
  float uu = u_ws[row*64 + k];
  float b2v = b2_g[k];
  float z = uu;
  __syncthreads();
  #pragma unroll
  for (int itr = 0; itr < 2; ++itr){
    zbuf[w][k] = z;
    float p0=0.f,p1=0.f,p2=0.f,p3=0.f;
    #pragma unroll
    for (int j0 = 0; j0 < 64; j0 += 4){
      float4 zz = *(const float4*)&zbuf[w][j0];
      p0 = fmaf(zz.x, A_g[(j0+0)*64 + k], p0);
      p1 = fmaf(zz.y, A_g[(j0+1)*64 + k], p1);
      p2 = fmaf(zz.z, A_g[(j0+2)*64 + k], p2);
      p3 = fmaf(zz.w, A_g[(j0+3)*64 + k], p3);
    }
    float p = (p0+p1)+(p2+p3);
    float a0=0.f, a1=0.f;
    #pragma unroll 8
    for (int j = 0; j < 64; j += 2){
      float pre0 = fmaf(p, w1t0[j*64+k],     fmaf(uu, w1t1[j*64+k],     b1tg[j*64+k]));
      float pre1 = fmaf(p, w1t0[(j+1)*64+k], fmaf(uu, w1t1[(j+1)*64+k], b1tg[(j+1)*64+k]));
      a0 = fmaf(gelu_f(pre0), w2tg[j*64+k],     a0);
      a1 = fmaf(gelu_f(pre1), w2tg[(j+1)*64+k], a1);
    }
    z = a0 + a1 + b2v;
  }
  zc_out[row*64 + k] = z;
  float sq = z*z;
  #pragma unroll
  for (int off = 1; off < 64; off <<= 1) sq += __shfl_xor(sq, off);
  if (k == 0) xnc[row] = sq;
}

// ---------------- domain head: gelu, mu/lv, z_d, KL + zd row-norm ----------------
__global__ __launch_bounds__(256) void k_domain(const float* __restrict__ dh_ws,
    const float* __restrict__ Wmu, const float* __restrict__ bmu,
    const float* __restrict__ Wlv, const float* __restrict__ blv,
    const float* __restrict__ eps, float* __restrict__ out, double* __restrict__ wsd,
    float* __restrict__ xnd){
  __shared__ float hb[4][64];
  int t = threadIdx.x, w = t >> 6, l = t & 63;
  int dd = l & 15;
  double klacc = 0.0;
  for (int it = 0; it < 4; ++it){
    int row = blockIdx.x*16 + it*4 + w;
    hb[w][l] = gelu_f(dh_ws[row*64 + l]);
    float val = 0.0f;
    if (l < 32){
      const float* W = (l < 16) ? Wmu : Wlv;
      float a = (l < 16) ? bmu[dd] : blv[dd];
      for (int j = 0; j < 64; j++) a = fmaf(hb[w][j], W[j*16 + dd], a);
      val = a;
    }
    float mu = __shfl(val, dd);
    float lv = __shfl(val, 16 + dd);
    float kle = 0.0f, zs = 0.0f;
    if (l < 16){
      out[O_MU + row*16 + dd] = mu;
      out[O_LV + row*16 + dd] = lv;
      float zdv = fmaf(eps[row*16 + dd], __expf(0.5f*lv), mu);
      out[O_ZD + row*16 + dd] = zdv;
      zs = zdv*zdv;
      kle = 1.0f + lv - mu*mu - __expf(lv);
    }
    #pragma unroll
    for (int off = 1; off < 16; off <<= 1){ kle += __shfl_xor(kle, off); zs += __shfl_xor(zs, off); }
    if (l == 0){ klacc += (double)kle; xnd[row] = zs; }
  }
  if (l == 0) atomicAdd(&wsd[1], klacc);
}

// ---------------- tile staging + 8x8 dot micro-kernel ----------------
template<int DIM>
__device__ __forceinline__ void stageT(const float* __restrict__ src, float* __restrict__ dst,
                                       int i0, int t){
  for (int e = t; e < DIM*128; e += 256){
    int k = e & (DIM-1);
    int r = e >> (DIM == 64 ? 6 : 4);
    dst[k*128 + (r ^ ((k & 7) << 2))] = src[(i0 + r)*DIM + k];
  }
}

template<int KDIM>
__device__ __forceinline__ void dot8x8(const float* __restrict__ LA, const float* __restrict__ LB,
                                       int tx8, int ty8, float acc[8][8]){
  #pragma unroll 8
  for (int k = 0; k < KDIM; k++){
    int s = (k & 7) << 2;
    const float* pa = LA + k*128;
    const float* pb = LB + k*128;
    float4 a0 = *(const float4*)(pa + ((ty8    ) ^ s));
    float4 a1 = *(const float4*)(pa + ((ty8 + 4) ^ s));
    float4 b0 = *(const float4*)(pb + ((tx8    ) ^ s));
    float4 b1 = *(const float4*)(pb + ((tx8 + 4) ^ s));
    float av[8] = {a0.x,a0.y,a0.z,a0.w,a1.x,a1.y,a1.z,a1.w};
    float bv[8] = {b0.x,b0.y,b0.z,b0.w,b1.x,b1.y,b1.z,b1.w};
    #pragma unroll
    for (int ii = 0; ii < 8; ii++)
      #pragma unroll
      for (int jj = 0; jj < 8; jj++)
        acc[ii][jj] = fmaf(av[ii], bv[jj], acc[ii][jj]);
  }
}

// ---------------- dag: expm via scaling & squaring (single block) ----------------
__device__ void dag_mm(float* __restrict__ C, const float* __restrict__ Am, const float* __restrict__ Bm,
                       const float* __restrict__ Xm, float cI, float cX, int t, bool addG){
  int tx = t & 15, ty = t >> 4;
  float acc[4][4] = {};
  for (int k0 = 0; k0 < 64; k0 += 4){
    float4 a0 = *(const float4*)&Am[(ty*4+0)*64 + k0];
    float4 a1 = *(const float4*)&Am[(ty*4+1)*64 + k0];
    float4 a2 = *(const float4*)&Am[(ty*4+2)*64 + k0];
    float4 a3 = *(const float4*)&Am[(ty*4+3)*64 + k0];
    float4 b0 = *(const float4*)&Bm[(k0+0)*64 + tx*4];
    float4 b1 = *(const float4*)&Bm[(k0+1)*64 + tx*4];
    float4 b2 = *(const float4*)&Bm[(k0+2)*64 + tx*4];
    float4 b3 = *(const float4*)&Bm[(k0+3)*64 + tx*4];
#define MQ(ii, AV) \
    acc[ii][0] = fmaf(AV.x,b0.x, fmaf(AV.y,b1.x, fmaf(AV.z,b2.x, fmaf(AV.w,b3.x, acc[ii][0])))); \
    acc[ii][1] = fmaf(AV.x,b0.y, fmaf(AV.y,b1.y, fmaf(AV.z,b2.y, fmaf(AV.w,b3.y, acc[ii][1])))); \
    acc[ii][2] = fmaf(AV.x,b0.z, fmaf(AV.y,b1.z, fmaf(AV.z,b2.z, fmaf(AV.w,b3.z, acc[ii][2])))); \
    acc[ii][3] = fmaf(AV.x,b0.w, fmaf(AV.y,b1.w, fmaf(AV.z,b2.w, fmaf(AV.w,b3.w, acc[ii][3]))));
    MQ(0,a0) MQ(1,a1) MQ(2,a2) MQ(3,a3)
#undef MQ
  }
  #pragma unroll
  for (int ii = 0; ii < 4; ii++)
    #pragma unroll
    for (int jj = 0; jj < 4; jj++){
      int i = ty*4 + ii, j = tx*4 + jj;
      float v = acc[ii][jj];
      if (addG) v += ((i == j) ? cI : 0.0f) + cX * Xm[i*64 + j];
      C[i*64 + j] = v;
    }
  __syncthreads();
}

__device__ void dag_expm(float* ldsA, float* ldsB, const float* __restrict__ A_g,
                         float* __restrict__ dout){
  int t = threadIdx.x;
  float* X  = ldsA;
  float* X2 = ldsA + 4096;
  float* P  = ldsB;
  float* Pn = ldsB + 4096;
  for (int e = t; e < 4096; e += 256){ float a = A_g[e]; X[e] = a*a; }
  __syncthreads();
  int l = t & 63;
  float cs = 0.0f;
  for (int i = 0; i < 64; i++) cs += X[i*64 + l];
  #pragma unroll
  for (int off = 1; off < 64; off <<= 1) cs = fmaxf(cs, __shfl_xor(cs, off));
  int s_ = 0;
  if (cs > 2.0f) s_ = (int)ceilf(log2f(cs * 0.5f));
  if (s_ < 0) s_ = 0; if (s_ > 12) s_ = 12;
  float sc = exp2f((float)(-s_));
  __syncthreads();
  for (int e = t; e < 4096; e += 256) X[e] *= sc;
  __syncthreads();
  dag_mm(X2, X, X, X, 0.0f, 0.0f, t, false);
  const float C12 = 2.0876756987868099e-9f, C13 = 1.6059043836821613e-10f;
  for (int e = t; e < 4096; e += 256){
    int i = e >> 6, j = e & 63;
    P[e] = C13*X[e] + ((i == j) ? C12 : 0.0f);
  }
  __syncthreads();
  const float cf[12] = {1.0f, 1.0f, 0.5f, 1.0f/6.0f, 1.0f/24.0f, 1.0f/120.0f,
                        1.0f/720.0f, 1.0f/5040.0f, 1.0f/40320.0f, 1.0f/362880.0f,
                        1.0f/3628800.0f, 1.0f/39916800.0f};
  #pragma unroll
  for (int g = 5; g >= 0; --g){
    dag_mm(Pn, X2, P, X, cf[2*g], cf[2*g+1], t, true);
    float* tmp = P; P = Pn; Pn = tmp;
  }
  for (int q = 0; q < s_; ++q){
    dag_mm(Pn, P, P, X, 0.0f, 0.0f, t, false);
    float* tmp = P; P = Pn; Pn = tmp;
  }
  if (t < 64){
    float tr = P[t*65];
    #pragma unroll
    for (int off = 1; off < 64; off <<= 1) tr += __shfl_xor(tr, off);
    if (t == 0) dout[O_DAG] = tr - 64.0f;
  }
}

// ---------------- median pass 1: exponent histogram (256 bins x 32 LDS reps, 8 XCD replicas) ----------------
__global__ __launch_bounds__(256,1) void k_pass1(const float* __restrict__ out,
    const float* __restrict__ xnc, const float* __restrict__ xnd,
    unsigned* __restrict__ h1c, unsigned* __restrict__ h1d,
    float* __restrict__ dout){
  __shared__ __align__(16) float ldsA[8192];
  __shared__ __align__(16) float ldsB[8192];
  int t = threadIdx.x;
  if (blockIdx.x == 528){ dag_expm(ldsA, ldsB, out + O_A, dout); return; }
  int bi, bj; tri_map(blockIdx.x, bi, bj);
  bool diag = (bi == bj);
  int i0 = bi*128, j0 = bj*128;
  int tx = t & 15, ty = t >> 4, tx8 = tx*8, ty8 = ty*8;
  int rep = t & 31;
  int xrep = (blockIdx.x & 7) * 256;
  unsigned* hist = (unsigned*)ldsA;     // 256 bins x 32 reps = 8192 u32, reused after dots
  stageT<64>(out + O_ZC, ldsA, i0, t);
  stageT<64>(out + O_ZC, ldsB, j0, t);
  float xi[8], xj[8];
  #pragma unroll
  for (int ii = 0; ii < 8; ii++){ xi[ii] = xnc[i0+ty8+ii]; xj[ii] = xnc[j0+tx8+ii]; }
  __syncthreads();
  float acc[8][8] = {};
  dot8x8<64>(ldsA, ldsB, tx8, ty8, acc);
  __syncthreads();
  for (int e = t; e < 8192; e += 256) hist[e] = 0u;
  __syncthreads();
  #pragma unroll
  for (int ii = 0; ii < 8; ii++)
    #pragma unroll
    for (int jj = 0; jj < 8; jj++){
      float d2 = xi[ii] + xj[jj] - 2.0f*acc[ii][jj];
      bool take = diag ? ((i0+ty8+ii) < (j0+tx8+jj)) : true;
      if (take && d2 > 0.0f)
        atomicAdd(&hist[((__float_as_uint(d2) >> 23) << 5) | rep], 1u);
    }
  __syncthreads();
  {
    int b = (t + blockIdx.x*37) & 255;
    unsigned s = 0;
    #pragma unroll
    for (int rr = 0; rr < 32; rr++) s += hist[(b << 5) | ((rr + t) & 31)];
    if (s) atomicAdd(&h1c[xrep + b], s);
  }
  __syncthreads();
  // d phase
  stageT<16>(out + O_ZD, ldsB, i0, t);
  stageT<16>(out + O_ZD, ldsB + 2048, j0, t);
  #pragma unroll
  for (int ii = 0; ii < 8; ii++){ xi[ii] = xnd[i0+ty8+ii]; xj[ii] = xnd[j0+tx8+ii]; }
  __syncthreads();
  float acd[8][8] = {};
  dot8x8<16>(ldsB, ldsB + 2048, tx8, ty8, acd);
  __syncthreads();
  for (int e = t; e < 8192; e += 256) hist[e] = 0u;
  __syncthreads();
  #pragma unroll
  for (int ii = 0; ii < 8; ii++)
    #pragma unroll
    for (int jj = 0; jj < 8; jj++){
      float d2 = xi[ii] + xj[jj] - 2.0f*acd[ii][jj];
      bool take = diag ? ((i0+ty8+ii) < (j0+tx8+jj)) : true;
      if (take && d2 > 0.0f)
        atomicAdd(&hist[((__float_as_uint(d2) >> 23) << 5) | rep], 1u);
    }
  __syncthreads();
  {
    int b = (t + blockIdx.x*53) & 255;
    unsigned s = 0;
    #pragma unroll
    for (int rr = 0; rr < 32; rr++) s += hist[(b << 5) | ((rr + t) & 31)];
    if (s) atomicAdd(&h1d[xrep + b], s);
  }
}

// find target exponent bin + rank: h1 is 8 replicas x 256 bins
__device__ unsigned find_bin256(const unsigned* __restrict__ h1, unsigned* sbuf, int t,
                                unsigned* k2out){
  unsigned part = 0;
  #pragma unroll
  for (int r = 0; r < 8; r++) part += h1[r*256 + t];
  sbuf[t] = part;
  __syncthreads();
  for (int off = 1; off < 256; off <<= 1){
    unsigned v = (t >= off) ? sbuf[t-off] : 0u;
    __syncthreads();
    sbuf[t] += v;
    __syncthreads();
  }
  unsigned total = sbuf[255];
  unsigned pre = sbuf[t] - part;
  __syncthreads();
  if (t == 0){ sbuf[0] = 0xFFFFFFFFu; sbuf[1] = 0u; }
  __syncthreads();
  if (total > 0){
    unsigned rt = (total - 1u) >> 1;   // lower median rank
    if (rt >= pre && rt < pre + part){ sbuf[0] = (unsigned)t; sbuf[1] = rt - pre; }
  }
  __syncthreads();
  unsigned b1 = sbuf[0];
  unsigned k2 = sbuf[1];
  __syncthreads();
  if (k2out) *k2out = k2;
  return b1;
}

// ---------------- median pass 2: mantissa bits [22:13] (1024 bins x 8 LDS reps, 8 XCD replicas) ----------------
__global__ __launch_bounds__(256,1) void k_pass2(const float* __restrict__ out,
    const float* __restrict__ xnc, const float* __restrict__ xnd,
    const unsigned* __restrict__ h1c, const unsigned* __restrict__ h1d,
    unsigned long long* __restrict__ m2c, unsigned long long* __restrict__ m2d){
  __shared__ __align__(16) float ldsA[8192];
  __shared__ __align__(16) float ldsB[8192];
  unsigned* hist = (unsigned*)ldsA;            // 1024 bins x 8 reps = 8192 u32
  int t = threadIdx.x;
  int rep = t & 7;
  int xrep = (blockIdx.x & 7) * 512;           // u64 slots per replica
  unsigned b1c = find_bin256(h1c, (unsigned*)ldsA, t, nullptr);
  unsigned b1d = find_bin256(h1d, (unsigned*)ldsA, t, nullptr);
  int bi, bj; tri_map(blockIdx.x, bi, bj);
  bool diag = (bi == bj);
  int i0 = bi*128, j0 = bj*128;
  int tx = t & 15, ty = t >> 4, tx8 = tx*8, ty8 = ty*8;
  // ---- c phase ----
  stageT<64>(out + O_ZC, ldsA, i0, t);
  stageT<64>(out + O_ZC, ldsB, j0, t);
  float xi[8], xj[8];
  #pragma unroll
  for (int ii = 0; ii < 8; ii++){ xi[ii] = xnc[i0+ty8+ii]; xj[ii] = xnc[j0+tx8+ii]; }
  __syncthreads();
  float acc[8][8] = {};
  dot8x8<64>(ldsA, ldsB, tx8, ty8, acc);
  __syncthreads();
  for (int e = t; e < 8192; e += 256) hist[e] = 0u;
  __syncthreads();
  #pragma unroll
  for (int ii = 0; ii < 8; ii++)
    #pragma unroll
    for (int jj = 0; jj < 8; jj++){
      float d2 = xi[ii] + xj[jj] - 2.0f*acc[ii][jj];
      unsigned u = __float_as_uint(d2);
      bool take = (diag ? ((i0+ty8+ii) < (j0+tx8+jj)) : true) && d2 > 0.0f && (u >> 23) == b1c;
      if (take) atomicAdd(&hist[(((u >> 13) & 0x3FFu) << 3) | rep], 1u);
    }
  __syncthreads();
  for (int e = t; e < 512; e += 256){
    int idx = (e + blockIdx.x*37) & 511;
    unsigned lo = 0, hi = 0;
    #pragma unroll
    for (int rr = 0; rr < 8; rr++){ lo += hist[(2*idx)*8 + rr]; hi += hist[(2*idx+1)*8 + rr]; }
    if (lo | hi)
      atomicAdd(&m2c[xrep + idx], (unsigned long long)lo | ((unsigned long long)hi << 32));
  }
  __syncthreads();
  // ---- d phase ----
  stageT<16>(out + O_ZD, ldsB, i0, t);
  stageT<16>(out + O_ZD, ldsB + 2048, j0, t);
  #pragma unroll
  for (int ii = 0; ii < 8; ii++){ xi[ii] = xnd[i0+ty8+ii]; xj[ii] = xnd[j0+tx8+ii]; }
  __syncthreads();
  float acd[8][8] = {};
  dot8x8<16>(ldsB, ldsB + 2048, tx8, ty8, acd);
  __syncthreads();
  for (int e = t; e < 8192; e += 256) hist[e] = 0u;
  __syncthreads();
  #pragma unroll
  for (int ii = 0; ii < 8; ii++)
    #pragma unroll
    for (int jj = 0; jj < 8; jj++){
      float d2 = xi[ii] + xj[jj] - 2.0f*acd[ii][jj];
      unsigned u = __float_as_uint(d2);
      bool take = (diag ? ((i0+ty8+ii) < (j0+tx8+jj)) : true) && d2 > 0.0f && (u >> 23) == b1d;
      if (take) atomicAdd(&hist[(((u >> 13) & 0x3FFu) << 3) | rep], 1u);
    }
  __syncthreads();
  for (int e = t; e < 512; e += 256){
    int idx = (e + blockIdx.x*53) & 511;
    unsigned lo = 0, hi = 0;
    #pragma unroll
    for (int rr = 0; rr < 8; rr++){ lo += hist[(2*idx)*8 + rr]; hi += hist[(2*idx+1)*8 + rr]; }
    if (lo | hi)
      atomicAdd(&m2d[xrep + idx], (unsigned long long)lo | ((unsigned long long)hi << 32));
  }
}

// ---------------- median finalize: exponent + 10 mantissa bits -> midpoint -> gamma ----------------
__global__ __launch_bounds__(256) void k_scan2(const unsigned* __restrict__ h1c,
    const unsigned* __restrict__ h1d, const unsigned* __restrict__ m2c,
    const unsigned* __restrict__ m2d, float* __restrict__ wsf){
  __shared__ unsigned sbuf[256];
  __shared__ unsigned res[2];
  int t = threadIdx.x;
  bool isd = blockIdx.x != 0;
  const unsigned* h1 = isd ? h1d : h1c;
  const unsigned* m2 = isd ? m2d : m2c;   // u32 view: 8 replicas x 1024 bins
  unsigned k2;
  unsigned b1 = find_bin256(h1, sbuf, t, &k2);
  if (b1 == 0xFFFFFFFFu){
    if (t == 0) wsf[8 + blockIdx.x] = 0.5f;   // cnt==0 -> sigma=1
    return;
  }
  // sum replicas: 4 bins per thread
  unsigned bsum[4];
  unsigned part = 0;
  #pragma unroll
  for (int i = 0; i < 4; i++){
    unsigned b = t*4 + i;
    unsigned s = 0;
    #pragma unroll
    for (int r = 0; r < 8; r++) s += m2[r*1024 + b];
    bsum[i] = s; part += s;
  }
  sbuf[t] = part; __syncthreads();
  for (int off = 1; off < 256; off <<= 1){
    unsigned v = (t >= off) ? sbuf[t-off] : 0u; __syncthreads(); sbuf[t] += v; __syncthreads();
  }
  unsigned pre = sbuf[t] - part;
  __syncthreads();
  if (t == 0) res[0] = 0u;
  __syncthreads();
  if (k2 >= pre && k2 < pre + part){
    unsigned run = pre;
    #pragma unroll
    for (int i = 0; i < 4; i++){
      if (k2 < run + bsum[i]){ res[0] = (unsigned)(t*4 + i); break; }
      run += bsum[i];
    }
  }
  __syncthreads();
  if (t == 0){
    unsigned med_bits = (b1 << 23) | (res[0] << 13) | 4096u;   // midpoint, rel err ~5e-4
    float med = __uint_as_float(med_bits);
    float sig = fmaxf(sqrtf(med), 1e-6f);
    wsf[8 + blockIdx.x] = 1.0f/(2.0f*sig*sig);
  }
}

// ---------------- HSIC accumulation pass (triangle) ----------------
__global__ __launch_bounds__(256,1) void k_hsic(const float* __restrict__ out,
    const float* __restrict__ xnc, const float* __restrict__ xnd,
    const float* __restrict__ wsf, double* __restrict__ wsd,
    float* __restrict__ rsc, float* __restrict__ rsd){
  __shared__ __align__(16) float ldsA[8192];
  __shared__ __align__(16) float ldsB[8192];
  int t = threadIdx.x;
  int bi, bj; tri_map(blockIdx.x, bi, bj);
  bool diag = (bi == bj);
  int i0 = bi*128, j0 = bj*128;
  int tx = t & 15, ty = t >> 4, tx8 = tx*8, ty8 = ty*8;
  float gc = wsf[8], gd = wsf[9];
  stageT<64>(out + O_ZC, ldsA, i0, t);
  stageT<64>(out + O_ZC, ldsB, j0, t);
  float xi[8], xj[8];
  #pragma unroll
  for (int ii = 0; ii < 8; ii++){ xi[ii] = xnc[i0+ty8+ii]; xj[ii] = xnc[j0+tx8+ii]; }
  __syncthreads();
  float kc[8][8] = {};
  dot8x8<64>(ldsA, ldsB, tx8, ty8, kc);
  #pragma unroll
  for (int ii = 0; ii < 8; ii++)
    #pragma unroll
    for (int jj = 0; jj < 8; jj++)
      kc[ii][jj] = __expf(-gc * fmaxf(xi[ii] + xj[jj] - 2.0f*kc[ii][jj], 0.0f));
  __syncthreads();
  stageT<16>(out + O_ZD, ldsA, i0, t);
  stageT<16>(out + O_ZD, ldsA + 2048, j0, t);
  #pragma unroll
  for (int ii = 0; ii < 8; ii++){ xi[ii] = xnd[i0+ty8+ii]; xj[ii] = xnd[j0+tx8+ii]; }
  __syncthreads();
  float ad[8][8] = {};
  dot8x8<16>(ldsA, ldsA + 2048, tx8, ty8, ad);
  float t1p = 0.0f;
  float rc[8] = {}, rd[8] = {}, cc[8] = {}, cd[8] = {};
  #pragma unroll
  for (int ii = 0; ii < 8; ii++)
    #pragma unroll
    for (int jj = 0; jj < 8; jj++){
      float kd = __expf(-gd * fmaxf(xi[ii] + xj[jj] - 2.0f*ad[ii][jj], 0.0f));
      float c = kc[ii][jj];
      t1p = fmaf(c, kd, t1p);
      rc[ii] += c; rd[ii] += kd;
      cc[jj] += c; cd[jj] += kd;
    }
  __syncthreads();
  float* red = ldsB;           // [0,128)rowC [128,256)rowD [256,384)colC [384,512)colD [512,516)t1
  red[t] = 0.0f; red[t + 256] = 0.0f;
  __syncthreads();
  #pragma unroll
  for (int ii = 0; ii < 8; ii++){
    atomicAdd(&red[ty8 + ii], rc[ii]);
    atomicAdd(&red[128 + ty8 + ii], rd[ii]);
  }
  if (!diag){
    #pragma unroll
    for (int jj = 0; jj < 8; jj++){
      atomicAdd(&red[256 + tx8 + jj], cc[jj]);
      atomicAdd(&red[384 + tx8 + jj], cd[jj]);
    }
  }
  #pragma unroll
  for (int off = 1; off < 64; off <<= 1) t1p += __shfl_xor(t1p, off);
  if ((t & 63) == 0) red[512 + (t >> 6)] = t1p;
  __syncthreads();
  if (t < 128){ atomicAdd(&rsc[i0 + t], red[t]); atomicAdd(&rsd[i0 + t], red[128 + t]); }
  else if (!diag){ atomicAdd(&rsc[j0 + t - 128], red[256 + t - 128]); atomicAdd(&rsd[j0 + t - 128], red[384 + t - 128]); }
  if (t == 0){
    double s = (double)red[512] + (double)red[513] + (double)red[514] + (double)red[515];
    if (!diag) s *= 2.0;
    atomicAdd(&wsd[0], s);
  }
}

// ---------------- final combine ----------------
__global__ __launch_bounds__(256) void k_combine(const double* __restrict__ wsd,
    const float* __restrict__ rsc, const float* __restrict__ rsd, float* __restrict__ dout){
  __shared__ double r1[256], r2[256], r3[256];
  int t = threadIdx.x;
  double sc = 0.0, sd = 0.0, pp = 0.0;
  for (int i = t; i < 4096; i += 256){
    double a = rsc[i], b = rsd[i];
    sc += a; sd += b; pp += a*b;
  }
  r1[t] = sc; r2[t] = sd; r3[t] = pp; __syncthreads();
  for (int off = 128; off > 0; off >>= 1){
    if (t < off){ r1[t] += r1[t+off]; r2[t] += r2[t+off]; r3[t] += r3[t+off]; }
    __syncthreads();
  }
  if (t == 0){
    double n = 4096.0;
    double T1 = wsd[0];
    double hs = (T1 - 2.0*r3[0]/n + r1[0]*r2[0]/(n*n)) / ((n-1.0)*(n-1.0));
    dout[O_HSIC] = (float)hs;
    dout[O_KL]   = (float)(-0.5 * wsd[1] / n);
  }
}

// ---------------- launcher ----------------
extern "C" void kernel_launch(void* const* d_in, const int* in_sizes, int n_in,
                              void* d_out, int out_size, void* d_ws, size_t ws_size,
                              hipStream_t stream){
  (void)in_sizes; (void)n_in; (void)out_size; (void)ws_size;
  const float* feat  = (const float*)d_in[0];
  const float* ln_g  = (const float*)d_in[1];
  const float* ln_b  = (const float*)d_in[2];
  const float* W_u   = (const float*)d_in[3];
  const float* b_u   = (const float*)d_in[4];
  const float* W1    = (const float*)d_in[5];
  const float* b1    = (const float*)d_in[6];
  const float* W2    = (const float*)d_in[7];
  const float* b2    = (const float*)d_in[8];
  const float* adj   = (const float*)d_in[9];
  const float* dln_g = (const float*)d_in[10];
  const float* dln_b = (const float*)d_in[11];
  const float* W_db  = (const float*)d_in[12];
  const float* b_db  = (const float*)d_in[13];
  const float* W_mu  = (const float*)d_in[14];
  const float* b_mu  = (const float*)d_in[15];
  const float* W_lv  = (const float*)d_in[16];
  const float* b_lv  = (const float*)d_in[17];
  const float* eps   = (const float*)d_in[18];
  float* out = (float*)d_out;
  char* ws = (char*)d_ws;
  float*  wsf = (float*)ws;
  double* wsd = (double*)ws;
  unsigned* h1c  = (unsigned*)(ws + WS_H1C);
  unsigned* h1d  = (unsigned*)(ws + WS_H1D);
  unsigned* m2c  = (unsigned*)(ws + WS_M2C);
  unsigned* m2d  = (unsigned*)(ws + WS_M2D);
  float* rsc  = (float*)(ws + WS_RSC);
  float* rsd  = (float*)(ws + WS_RSD);
  float* xnc  = (float*)(ws + WS_XNC);
  float* xnd  = (float*)(ws + WS_XND);
  float* Wc   = (float*)(ws + WS_WC);
  float* cst  = (float*)(ws + WS_CST);
  float* w1t0 = (float*)(ws + WS_W1T0);
  float* w1t1 = (float*)(ws + WS_W1T1);
  float* b1t  = (float*)(ws + WS_B1T);
  float* w2t  = (float*)(ws + WS_W2T);
  float* u_ws = (float*)(ws + WS_U);
  float* dh_ws= (float*)(ws + WS_DH);

  k_zero<<<dim3(64), dim3(256), 0, stream>>>((uint4*)ws, (int)(WS_ZEND/16u));
  k_prep<<<dim3(720), dim3(256), 0, stream>>>(ln_g, ln_b, W_u, b_u, dln_g, dln_b, W_db, b_db,
                                              adj, W1, b1, W2, Wc, cst, w1t0, w1t1, b1t, w2t,
                                              out + O_A);
  k_lngemm<<<dim3(256), dim3(512), 0, stream>>>(feat, Wc, cst, u_ws, dh_ws);
  k_causal<<<dim3(1024), dim3(256), 0, stream>>>(u_ws, out + O_A, w1t0, w1t1, b1t, w2t, b2,
                                                 out + O_ZC, xnc);
  k_domain<<<dim3(256), dim3(256), 0, stream>>>(dh_ws, W_mu, b_mu, W_lv, b_lv, eps, out, wsd,
                                                xnd);
  k_pass1<<<dim3(529), dim3(256), 0, stream>>>(out, xnc, xnd, h1c, h1d, out);
  k_pass2<<<dim3(528), dim3(256), 0, stream>>>(out, xnc, xnd, h1c, h1d,
                                               (unsigned long long*)m2c,
                                               (unsigned long long*)m2d);
  k_scan2<<<dim3(2), dim3(256), 0, stream>>>(h1c, h1d, m2c, m2d, wsf);
  k_hsic<<<dim3(528), dim3(256), 0, stream>>>(out, xnc, xnd, wsf, wsd, rsc, rsd);
  k_combine<<<dim3(1), dim3(256), 0, stream>>>(wsd, rsc, rsd, out);
}